// Round 1
// baseline (1865.991 us; speedup 1.0000x reference)
//
#include <hip/hip_runtime.h>

#define NP 50000
#define NU 100000
#define NS 20000

// ---------------------------------------------------------------------------
// init: xs[t] = x @ lin_w[t] + lin_b[t] + emb[node_id]
// grid = N blocks, 128 threads (thread = output dim)
// ---------------------------------------------------------------------------
__global__ __launch_bounds__(128) void k_init(const float* __restrict__ x,
                                              const float* __restrict__ lw,
                                              const float* __restrict__ lb,
                                              const float* __restrict__ emb,
                                              const int* __restrict__ nid,
                                              float* __restrict__ out, int N) {
  int n = blockIdx.x;
  int d = threadIdx.x;
  if (n >= N) return;
  float s = lb[d];
#pragma unroll
  for (int j = 0; j < 20; ++j) s += x[n * 20 + j] * lw[j * 128 + d];
  out[n * 128 + d] = s + emb[nid[n] * 128 + d];
}

// ---------------------------------------------------------------------------
// Keff[c][d] = sum_f Wk[c][f] * We[d][f];  bkeff[d] = sum_f bk[f]*We[d][f]
// grid = 128 blocks (c), 128 threads (d). We staged in LDS (f-tiles of 64).
// ---------------------------------------------------------------------------
__global__ __launch_bounds__(128) void k_keff(const float* __restrict__ Wk,
                                              const float* __restrict__ bk,
                                              const float* __restrict__ We,
                                              float* __restrict__ Keff,
                                              float* __restrict__ bkeff) {
  __shared__ float Wes[128][65];
  int c = blockIdx.x, tid = threadIdx.x;
  float s = 0.f, t = 0.f;
  for (int f0 = 0; f0 < 128; f0 += 64) {
    __syncthreads();
    int fr = tid & 63, r0 = tid >> 6;
    for (int it = 0; it < 64; ++it) {
      int row = it * 2 + r0;
      Wes[row][fr] = We[row * 128 + f0 + fr];
    }
    __syncthreads();
#pragma unroll 16
    for (int fp = 0; fp < 64; ++fp) {
      s += Wk[c * 128 + f0 + fp] * Wes[tid][fp];
    }
    if (c == 0) {
      for (int fp = 0; fp < 64; ++fp) t += bk[f0 + fp] * Wes[tid][fp];
    }
  }
  Keff[c * 128 + tid] = s;
  if (c == 0) bkeff[tid] = t;
}

// ---------------------------------------------------------------------------
// Y[M,128] = X[M,128] @ W[128,128] + bias
// BM=128, BN=64 (grid.y=2), BK=64; 256 threads, thread tile 8x4
// ---------------------------------------------------------------------------
#define GM_BM 128
#define GM_BN 64
#define GM_BK 64
__global__ __launch_bounds__(256) void k_gemm128(const float* __restrict__ X,
                                                 const float* __restrict__ W,
                                                 const float* __restrict__ bias,
                                                 float* __restrict__ Y, int M) {
  __shared__ float Xs[GM_BK][GM_BM + 4];  // transposed: Xs[k][r], stride 132
  __shared__ float Ws[GM_BK][GM_BN];      // Ws[k][n]
  int tid = threadIdx.x;
  int row0 = blockIdx.x * GM_BM;
  int col0 = blockIdx.y * GM_BN;
  int tx = tid & 15;   // col quad: cols col0 + tx*4 .. +3
  int ty = tid >> 4;   // row oct : rows row0 + ty*8 .. +7

  float acc[8][4];
#pragma unroll
  for (int i = 0; i < 8; ++i)
#pragma unroll
    for (int j = 0; j < 4; ++j) acc[i][j] = 0.f;

  for (int kc = 0; kc < 128; kc += GM_BK) {
    // X tile: 128 rows x 64 k -> 2048 float4 slots, 8 per thread (transpose)
#pragma unroll
    for (int s = 0; s < 8; ++s) {
      int slot = tid + s * 256;
      int r = slot >> 4;
      int f4 = slot & 15;
      int grow = row0 + r;
      float4 v = make_float4(0.f, 0.f, 0.f, 0.f);
      if (grow < M) v = *(const float4*)&X[grow * 128 + kc + f4 * 4];
      Xs[f4 * 4 + 0][r] = v.x;
      Xs[f4 * 4 + 1][r] = v.y;
      Xs[f4 * 4 + 2][r] = v.z;
      Xs[f4 * 4 + 3][r] = v.w;
    }
    // W tile: 64 k x 64 n -> 1024 float4 slots, 4 per thread
#pragma unroll
    for (int s = 0; s < 4; ++s) {
      int slot = tid + s * 256;
      int k = slot >> 4;
      int f4 = slot & 15;
      *(float4*)&Ws[k][f4 * 4] = *(const float4*)&W[(kc + k) * 128 + col0 + f4 * 4];
    }
    __syncthreads();
#pragma unroll 8
    for (int k = 0; k < GM_BK; ++k) {
      float4 a0 = *(const float4*)&Xs[k][ty * 8];
      float4 a1 = *(const float4*)&Xs[k][ty * 8 + 4];
      float4 b4 = *(const float4*)&Ws[k][tx * 4];
      float a[8] = {a0.x, a0.y, a0.z, a0.w, a1.x, a1.y, a1.z, a1.w};
      float b[4] = {b4.x, b4.y, b4.z, b4.w};
#pragma unroll
      for (int i = 0; i < 8; ++i)
#pragma unroll
        for (int j = 0; j < 4; ++j) acc[i][j] += a[i] * b[j];
    }
    __syncthreads();
  }
#pragma unroll
  for (int i = 0; i < 8; ++i) {
    int r = row0 + ty * 8 + i;
    if (r < M) {
#pragma unroll
      for (int j = 0; j < 4; ++j)
        Y[r * 128 + col0 + tx * 4 + j] = acc[i][j] + bias[col0 + tx * 4 + j];
    }
  }
}

// ---------------------------------------------------------------------------
// edge scores: ex[e] = exp(leakyrelu(scale * dot(Q[src], K[dst])));
// den[dst] += ex[e].   16 lanes per edge.
// ---------------------------------------------------------------------------
__global__ __launch_bounds__(256) void k_scores(const int* __restrict__ ei, int E,
                                                const float* __restrict__ Q,
                                                const float* __restrict__ K,
                                                float* __restrict__ ex,
                                                float* __restrict__ den,
                                                float scale) {
  int t = blockIdx.x * 256 + threadIdx.x;
  int e = t >> 4;
  int sub = t & 15;
  if (e >= E) return;
  int src = ei[e];
  int dst = ei[E + e];
  const float4* q = (const float4*)&Q[src * 128 + sub * 8];
  const float4* k = (const float4*)&K[dst * 128 + sub * 8];
  float4 q0 = q[0], q1 = q[1], k0 = k[0], k1 = k[1];
  float p = q0.x * k0.x + q0.y * k0.y + q0.z * k0.z + q0.w * k0.w +
            q1.x * k1.x + q1.y * k1.y + q1.z * k1.z + q1.w * k1.w;
  p += __shfl_xor(p, 8, 16);
  p += __shfl_xor(p, 4, 16);
  p += __shfl_xor(p, 2, 16);
  p += __shfl_xor(p, 1, 16);
  if (sub == 0) {
    float s = p * scale;
    s = (s > 0.f) ? s : 0.01f * s;
    float v = expf(s);
    ex[e] = v;
    atomicAdd(&den[dst], v);
  }
}

// ---------------------------------------------------------------------------
// CSR build
// ---------------------------------------------------------------------------
__global__ void k_count(const int* __restrict__ dst, int E, int* __restrict__ counts) {
  int e = blockIdx.x * 256 + threadIdx.x;
  if (e < E) atomicAdd(&counts[dst[e]], 1);
}

__global__ __launch_bounds__(1024) void k_scan(const int* __restrict__ counts,
                                               int* __restrict__ rowptr, int N) {
  __shared__ int wsum[16];
  __shared__ int carry_s;
  int tid = threadIdx.x;
  int lane = tid & 63, w = tid >> 6;
  if (tid == 0) carry_s = 0;
  __syncthreads();
  for (int base = 0; base < N; base += 1024) {
    int i = base + tid;
    int v = (i < N) ? counts[i] : 0;
    int sv = v;
#pragma unroll
    for (int off = 1; off < 64; off <<= 1) {
      int u = __shfl_up(sv, off, 64);
      if (lane >= off) sv += u;
    }
    if (lane == 63) wsum[w] = sv;
    __syncthreads();
    if (w == 0) {
      int s = (lane < 16) ? wsum[lane] : 0;
#pragma unroll
      for (int off = 1; off < 16; off <<= 1) {
        int u = __shfl_up(s, off, 64);
        if (lane >= off) s += u;
      }
      if (lane < 16) wsum[lane] = s;
    }
    __syncthreads();
    int carry = carry_s;
    int woff = (w > 0) ? wsum[w - 1] : 0;
    if (i < N) rowptr[i + 1] = carry + woff + sv;
    __syncthreads();
    if (tid == 1023) carry_s = carry + wsum[15];
    __syncthreads();
  }
  if (tid == 0) rowptr[0] = 0;
}

__global__ void k_fill(const int* __restrict__ dst, int E,
                       const int* __restrict__ rowptr, int* __restrict__ cursor,
                       int* __restrict__ eids) {
  int e = blockIdx.x * 256 + threadIdx.x;
  if (e < E) {
    int d = dst[e];
    int p = atomicAdd(&cursor[d], 1);
    eids[rowptr[d] + p] = e;
  }
}

// ---------------------------------------------------------------------------
// aggregate: out[n][d] = relu?( (1/den[n]) * sum_e ex[e]*V[src_e][d] )
// one block (128 threads) per dst node
// ---------------------------------------------------------------------------
__global__ __launch_bounds__(128) void k_aggregate(const int* __restrict__ ei,
                                                   const int* __restrict__ rowptr,
                                                   const int* __restrict__ eids,
                                                   const float* __restrict__ ex,
                                                   const float* __restrict__ den,
                                                   const float* __restrict__ V,
                                                   float* __restrict__ out,
                                                   int relu_flag) {
  int n = blockIdx.x;
  int d = threadIdx.x;
  int s0 = rowptr[n], s1 = rowptr[n + 1];
  float acc = 0.f;
  float inv = (s1 > s0) ? 1.f / den[n] : 0.f;
  for (int k = s0; k < s1; ++k) {
    int e = eids[k];
    int src = ei[e];
    acc += ex[e] * V[src * 128 + d];
  }
  acc *= inv;
  if (relu_flag) acc = fmaxf(acc, 0.f);
  out[n * 128 + d] = acc;
}

// ---------------------------------------------------------------------------

extern "C" void kernel_launch(void* const* d_in, const int* in_sizes, int n_in,
                              void* d_out, int out_size, void* d_ws, size_t ws_size,
                              hipStream_t stream) {
  const float* x_in[3] = {(const float*)d_in[0], (const float*)d_in[1], (const float*)d_in[2]};
  const int* nid[3] = {(const int*)d_in[3], (const int*)d_in[4], (const int*)d_in[5]};
  const int* ei[3] = {(const int*)d_in[6], (const int*)d_in[7], (const int*)d_in[8]};
  const float* lin_w = (const float*)d_in[9];
  const float* lin_b = (const float*)d_in[10];
  const float* emb[3] = {(const float*)d_in[11], (const float*)d_in[12], (const float*)d_in[13]};
  const float* qkv_w = (const float*)d_in[14];
  const float* qkv_b = (const float*)d_in[15];
  const float* W_edge = (const float*)d_in[16];
  float* out = (float*)d_out;

  const int TYPE_N[3] = {NP, NU, NS};
  const int TYPE_OFF[3] = {0, NP, NP + NU};
  const int ET_SRC[3] = {1, 0, 2};
  const int ET_DST[3] = {0, 2, 1};
  const int ET_E[3] = {400000, 300000, 300000};

  // workspace carve-up (256B aligned)
  char* ws = (char*)d_ws;
  size_t o = 0;
  auto carve = [&](size_t bytes) {
    char* p = ws + o;
    o = (o + bytes + 255) & ~(size_t)255;
    return p;
  };
  float* xsA = (float*)carve((size_t)170000 * 128 * 4);
  float* xsB = (float*)carve((size_t)170000 * 128 * 4);
  float* qkvpool = (float*)carve((size_t)250000 * 128 * 4);  // Q|K|V packed per edge type
  float* Keff = (float*)carve(128 * 128 * 4);
  float* bkeff = (float*)carve(128 * 4);
  float* exb = (float*)carve(400000 * 4);
  float* den = (float*)carve(100000 * 4);
  int* cnt = (int*)carve(100000 * 4);
  int* rp[3];
  rp[0] = (int*)carve((NP + 1) * 4);
  rp[1] = (int*)carve((NS + 1) * 4);
  rp[2] = (int*)carve((NU + 1) * 4);
  int* eids[3];
  eids[0] = (int*)carve(400000 * 4);
  eids[1] = (int*)carve(300000 * 4);
  eids[2] = (int*)carve(300000 * 4);
  (void)ws_size;

  // ---- initial features ----
  for (int t = 0; t < 3; ++t) {
    k_init<<<TYPE_N[t], 128, 0, stream>>>(x_in[t], lin_w + t * 20 * 128, lin_b + t * 128,
                                          emb[t], nid[t], xsA + (size_t)TYPE_OFF[t] * 128,
                                          TYPE_N[t]);
  }

  // ---- CSR per edge type (by destination) ----
  for (int et = 0; et < 3; ++et) {
    int E = ET_E[et];
    int Nd = TYPE_N[ET_DST[et]];
    const int* dstp = ei[et] + E;
    hipMemsetAsync(cnt, 0, (size_t)Nd * 4, stream);
    k_count<<<(E + 255) / 256, 256, 0, stream>>>(dstp, E, cnt);
    k_scan<<<1, 1024, 0, stream>>>(cnt, rp[et], Nd);
    hipMemsetAsync(cnt, 0, (size_t)Nd * 4, stream);
    k_fill<<<(E + 255) / 256, 256, 0, stream>>>(dstp, E, rp[et], cnt, eids[et]);
  }

  const float scale = 0.08838834764831845f;  // 1/sqrt(128)

  for (int l = 0; l < 2; ++l) {
    const float* xin = (l == 0) ? xsA : xsB;
    float* xout = (l == 0) ? xsB : out;
    for (int et = 0; et < 3; ++et) {
      int st = ET_SRC[et], dt = ET_DST[et];
      int Ms = TYPE_N[st], Md = TYPE_N[dt];
      int E = ET_E[et];
      const float* Wq = qkv_w + (size_t)(((l * 3 + st) * 3 + 0)) * 16384;
      const float* bq = qkv_b + (size_t)(((l * 3 + st) * 3 + 0)) * 128;
      const float* Wk = qkv_w + (size_t)(((l * 3 + dt) * 3 + 1)) * 16384;
      const float* bk = qkv_b + (size_t)(((l * 3 + dt) * 3 + 1)) * 128;
      const float* Wv = qkv_w + (size_t)(((l * 3 + st) * 3 + 2)) * 16384;
      const float* bv = qkv_b + (size_t)(((l * 3 + st) * 3 + 2)) * 128;
      const float* We = W_edge + (size_t)(l * 3 + et) * 16384;

      float* Qb = qkvpool;
      float* Kb = qkvpool + (size_t)Ms * 128;
      float* Vb = qkvpool + (size_t)(Ms + Md) * 128;

      k_keff<<<128, 128, 0, stream>>>(Wk, bk, We, Keff, bkeff);

      dim3 gq((Ms + GM_BM - 1) / GM_BM, 2);
      dim3 gk((Md + GM_BM - 1) / GM_BM, 2);
      k_gemm128<<<gq, 256, 0, stream>>>(xin + (size_t)TYPE_OFF[st] * 128, Wq, bq, Qb, Ms);
      k_gemm128<<<gk, 256, 0, stream>>>(xin + (size_t)TYPE_OFF[dt] * 128, Keff, bkeff, Kb, Md);
      k_gemm128<<<gq, 256, 0, stream>>>(xin + (size_t)TYPE_OFF[st] * 128, Wv, bv, Vb, Ms);

      hipMemsetAsync(den, 0, (size_t)Md * 4, stream);
      k_scores<<<(E * 16 + 255) / 256, 256, 0, stream>>>(ei[et], E, Qb, Kb, exb, den, scale);
      k_aggregate<<<Md, 128, 0, stream>>>(ei[et], rp[et], eids[et], exb, den, Vb,
                                          xout + (size_t)TYPE_OFF[dt] * 128, (l == 0) ? 1 : 0);
    }
  }
}

// Round 3
// 1600.742 us; speedup vs baseline: 1.1657x; 1.1657x over previous
//
#include <hip/hip_runtime.h>

#define NP 50000
#define NU 100000
#define NS 20000

typedef __attribute__((ext_vector_type(8))) short short8;
typedef __attribute__((ext_vector_type(4))) float f32x4;
typedef unsigned int uint32;

__device__ inline ushort f2bf(float f) {
  uint32 u = __float_as_uint(f);
  uint32 r = (u + 0x7FFF + ((u >> 16) & 1)) >> 16;
  return (ushort)r;
}
__device__ inline float bf2f(ushort h) { return __uint_as_float(((uint32)h) << 16); }

// ---------------------------------------------------------------------------
// init: s = x @ lin_w + lin_b + emb[node_id]; write bf16 hi/lo split
// ---------------------------------------------------------------------------
__global__ __launch_bounds__(128) void k_init(const float* __restrict__ x,
                                              const float* __restrict__ lw,
                                              const float* __restrict__ lb,
                                              const float* __restrict__ emb,
                                              const int* __restrict__ nid,
                                              ushort* __restrict__ hi,
                                              ushort* __restrict__ lo, int N) {
  int n = blockIdx.x;
  int d = threadIdx.x;
  if (n >= N) return;
  float s = lb[d];
#pragma unroll
  for (int j = 0; j < 20; ++j) s += x[n * 20 + j] * lw[j * 128 + d];
  s += emb[nid[n] * 128 + d];
  ushort h = f2bf(s);
  hi[n * 128 + d] = h;
  lo[n * 128 + d] = f2bf(s - bf2f(h));
}

// ---------------------------------------------------------------------------
// Keff[c][d] = sum_f Wk[c][f] * We[d][f];  bkeff[d] = sum_f bk[f]*We[d][f]
// ---------------------------------------------------------------------------
__global__ __launch_bounds__(128) void k_keff(const float* __restrict__ Wk,
                                              const float* __restrict__ bk,
                                              const float* __restrict__ We,
                                              float* __restrict__ Keff,
                                              float* __restrict__ bkeff) {
  __shared__ float Wes[128][65];
  int c = blockIdx.x, tid = threadIdx.x;
  float s = 0.f, t = 0.f;
  for (int f0 = 0; f0 < 128; f0 += 64) {
    __syncthreads();
    int fr = tid & 63, r0 = tid >> 6;
    for (int it = 0; it < 64; ++it) {
      int row = it * 2 + r0;
      Wes[row][fr] = We[row * 128 + f0 + fr];
    }
    __syncthreads();
#pragma unroll 16
    for (int fp = 0; fp < 64; ++fp) {
      s += Wk[c * 128 + f0 + fp] * Wes[tid][fp];
    }
    if (c == 0) {
      for (int fp = 0; fp < 64; ++fp) t += bk[f0 + fp] * Wes[tid][fp];
    }
  }
  Keff[c * 128 + tid] = s;
  if (c == 0) bkeff[tid] = t;
}

// ---------------------------------------------------------------------------
// split + transpose 128x128 f32 weight(s) -> Wt[n][k] hi/lo bf16
// grid.x = 64, 256 threads; grid.y selects weight (src stride srcStride)
// ---------------------------------------------------------------------------
__global__ __launch_bounds__(256) void k_splitw(const float* __restrict__ W, int srcStride,
                                                ushort* __restrict__ hi,
                                                ushort* __restrict__ lo, int dstStride) {
  const float* src = W + (size_t)blockIdx.y * srcStride;
  ushort* h = hi + (size_t)blockIdx.y * dstStride;
  ushort* l = lo + (size_t)blockIdx.y * dstStride;
  int idx = blockIdx.x * 256 + threadIdx.x;  // 0..16383
  int n = idx >> 7, c = idx & 127;
  float f = src[c * 128 + n];
  ushort hb = f2bf(f);
  h[idx] = hb;
  l[idx] = f2bf(f - bf2f(hb));
}

// ---------------------------------------------------------------------------
// MFMA GEMM: Y[M,128] = A[M,128] @ B^T + bias, A = hi+lo bf16 split
// 256 threads = 4 waves; wave w -> cols 32w..32w+31; block -> 64 rows
// acc += Ah*Bh + Ah*Bl + Al*Bh  (f32 accumulate)
// ---------------------------------------------------------------------------
__global__ __launch_bounds__(256) void k_gemm(const ushort* __restrict__ Ahi,
                                              const ushort* __restrict__ Alo,
                                              const ushort* __restrict__ Bhi,
                                              const ushort* __restrict__ Blo,
                                              const float* __restrict__ bias,
                                              float* __restrict__ Y, int M) {
  int tid = threadIdx.x;
  int wave = tid >> 6, lane = tid & 63;
  int row0 = blockIdx.x * 64;
  int colw = wave * 32;
  int lrow = lane & 15, kgrp = lane >> 4;

  f32x4 acc[4][2] = {};

  int rows[4];
#pragma unroll
  for (int mt = 0; mt < 4; ++mt) {
    int r = row0 + mt * 16 + lrow;
    rows[mt] = (r < M) ? r : (M - 1);
  }

#pragma unroll
  for (int s = 0; s < 4; ++s) {
    int koff = s * 32 + kgrp * 8;
    short8 ah[4], al[4];
#pragma unroll
    for (int mt = 0; mt < 4; ++mt) {
      ah[mt] = *(const short8*)(Ahi + (size_t)rows[mt] * 128 + koff);
      al[mt] = *(const short8*)(Alo + (size_t)rows[mt] * 128 + koff);
    }
    short8 bh[2], bl[2];
#pragma unroll
    for (int nt = 0; nt < 2; ++nt) {
      int col = colw + nt * 16 + lrow;
      bh[nt] = *(const short8*)(Bhi + col * 128 + koff);
      bl[nt] = *(const short8*)(Blo + col * 128 + koff);
    }
#pragma unroll
    for (int mt = 0; mt < 4; ++mt)
#pragma unroll
      for (int nt = 0; nt < 2; ++nt) {
        acc[mt][nt] = __builtin_amdgcn_mfma_f32_16x16x32_bf16(ah[mt], bh[nt], acc[mt][nt], 0, 0, 0);
        acc[mt][nt] = __builtin_amdgcn_mfma_f32_16x16x32_bf16(ah[mt], bl[nt], acc[mt][nt], 0, 0, 0);
        acc[mt][nt] = __builtin_amdgcn_mfma_f32_16x16x32_bf16(al[mt], bh[nt], acc[mt][nt], 0, 0, 0);
      }
  }

#pragma unroll
  for (int mt = 0; mt < 4; ++mt) {
#pragma unroll
    for (int r = 0; r < 4; ++r) {
      int row = row0 + mt * 16 + kgrp * 4 + r;
      if (row < M) {
#pragma unroll
        for (int nt = 0; nt < 2; ++nt) {
          int col = colw + nt * 16 + lrow;
          Y[(size_t)row * 128 + col] = acc[mt][nt][r] + bias[col];
        }
      }
    }
  }
}

// ---------------------------------------------------------------------------
// edge scores
// ---------------------------------------------------------------------------
__global__ __launch_bounds__(256) void k_scores(const int* __restrict__ ei, int E,
                                                const float* __restrict__ Q,
                                                const float* __restrict__ K,
                                                float* __restrict__ ex,
                                                float* __restrict__ den, float scale) {
  int t = blockIdx.x * 256 + threadIdx.x;
  int e = t >> 4;
  int sub = t & 15;
  if (e >= E) return;
  int src = ei[e];
  int dst = ei[E + e];
  const float4* q = (const float4*)&Q[src * 128 + sub * 8];
  const float4* k = (const float4*)&K[dst * 128 + sub * 8];
  float4 q0 = q[0], q1 = q[1], k0 = k[0], k1 = k[1];
  float p = q0.x * k0.x + q0.y * k0.y + q0.z * k0.z + q0.w * k0.w +
            q1.x * k1.x + q1.y * k1.y + q1.z * k1.z + q1.w * k1.w;
  p += __shfl_xor(p, 8, 16);
  p += __shfl_xor(p, 4, 16);
  p += __shfl_xor(p, 2, 16);
  p += __shfl_xor(p, 1, 16);
  if (sub == 0) {
    float s = p * scale;
    s = (s > 0.f) ? s : 0.01f * s;
    float v = expf(s);
    ex[e] = v;
    atomicAdd(&den[dst], v);
  }
}

// ---------------------------------------------------------------------------
// CSR build: count -> hierarchical scan -> fill
// ---------------------------------------------------------------------------
__global__ void k_count(const int* __restrict__ dst, int E, int* __restrict__ counts) {
  int e = blockIdx.x * 256 + threadIdx.x;
  if (e < E) atomicAdd(&counts[dst[e]], 1);
}

__global__ __launch_bounds__(256) void k_blocksum(const int* __restrict__ c, int N,
                                                  int* __restrict__ bs) {
  int base = blockIdx.x * 1024;
  int t = threadIdx.x;
  int s = 0;
#pragma unroll
  for (int j = 0; j < 4; ++j) {
    int i = base + t * 4 + j;
    if (i < N) s += c[i];
  }
#pragma unroll
  for (int off = 32; off; off >>= 1) s += __shfl_down(s, off, 64);
  __shared__ int wsm[4];
  if ((t & 63) == 0) wsm[t >> 6] = s;
  __syncthreads();
  if (t == 0) bs[blockIdx.x] = wsm[0] + wsm[1] + wsm[2] + wsm[3];
}

__global__ __launch_bounds__(256) void k_scan_bsums(int* __restrict__ bs, int nb) {
  __shared__ int sm[256];
  int t = threadIdx.x;
  int v[4];
  int s = 0;
#pragma unroll
  for (int j = 0; j < 4; ++j) {
    int i = t * 4 + j;
    v[j] = (i < nb) ? bs[i] : 0;
    s += v[j];
  }
  sm[t] = s;
  __syncthreads();
  for (int off = 1; off < 256; off <<= 1) {
    int x = (t >= off) ? sm[t - off] : 0;
    __syncthreads();
    sm[t] += x;
    __syncthreads();
  }
  int run = t ? sm[t - 1] : 0;
#pragma unroll
  for (int j = 0; j < 4; ++j) {
    int i = t * 4 + j;
    if (i < nb) {
      int tmp = v[j];
      bs[i] = run;
      run += tmp;
    }
  }
}

__global__ __launch_bounds__(256) void k_scan_apply(const int* __restrict__ c,
                                                    const int* __restrict__ bofs,
                                                    int* __restrict__ rowptr, int N) {
  __shared__ int sm[256];
  int base = blockIdx.x * 1024, t = threadIdx.x;
  int v[4];
  int s = 0;
#pragma unroll
  for (int j = 0; j < 4; ++j) {
    int i = base + t * 4 + j;
    v[j] = (i < N) ? c[i] : 0;
    s += v[j];
  }
  sm[t] = s;
  __syncthreads();
  for (int off = 1; off < 256; off <<= 1) {
    int x = (t >= off) ? sm[t - off] : 0;
    __syncthreads();
    sm[t] += x;
    __syncthreads();
  }
  int run = bofs[blockIdx.x] + (t ? sm[t - 1] : 0);
#pragma unroll
  for (int j = 0; j < 4; ++j) {
    int i = base + t * 4 + j;
    if (i < N) {
      run += v[j];
      rowptr[i + 1] = run;
    }
  }
  if (blockIdx.x == 0 && t == 0) rowptr[0] = 0;
}

__global__ void k_fill(const int* __restrict__ dst, int E,
                       const int* __restrict__ rowptr, int* __restrict__ cursor,
                       int* __restrict__ eids) {
  int e = blockIdx.x * 256 + threadIdx.x;
  if (e < E) {
    int d = dst[e];
    int p = atomicAdd(&cursor[d], 1);
    eids[rowptr[d] + p] = e;
  }
}

// ---------------------------------------------------------------------------
// aggregate: MODE 0 -> relu + write bf16 hi/lo; MODE 1 -> write f32 (final)
// ---------------------------------------------------------------------------
template <int MODE>
__global__ __launch_bounds__(128) void k_aggregate(const int* __restrict__ ei,
                                                   const int* __restrict__ rowptr,
                                                   const int* __restrict__ eids,
                                                   const float* __restrict__ ex,
                                                   const float* __restrict__ den,
                                                   const float* __restrict__ V,
                                                   ushort* __restrict__ ohi,
                                                   ushort* __restrict__ olo,
                                                   float* __restrict__ of) {
  int n = blockIdx.x;
  int d = threadIdx.x;
  int s0 = rowptr[n], s1 = rowptr[n + 1];
  float acc = 0.f;
  float inv = (s1 > s0) ? 1.f / den[n] : 0.f;
  for (int k = s0; k < s1; ++k) {
    int e = eids[k];
    int src = ei[e];
    acc += ex[e] * V[src * 128 + d];
  }
  acc *= inv;
  if (MODE == 0) {
    acc = fmaxf(acc, 0.f);
    ushort h = f2bf(acc);
    ohi[n * 128 + d] = h;
    olo[n * 128 + d] = f2bf(acc - bf2f(h));
  } else {
    of[n * 128 + d] = acc;
  }
}

// ---------------------------------------------------------------------------

extern "C" void kernel_launch(void* const* d_in, const int* in_sizes, int n_in,
                              void* d_out, int out_size, void* d_ws, size_t ws_size,
                              hipStream_t stream) {
  const float* x_in[3] = {(const float*)d_in[0], (const float*)d_in[1], (const float*)d_in[2]};
  const int* nid[3] = {(const int*)d_in[3], (const int*)d_in[4], (const int*)d_in[5]};
  const int* ei[3] = {(const int*)d_in[6], (const int*)d_in[7], (const int*)d_in[8]};
  const float* lin_w = (const float*)d_in[9];
  const float* lin_b = (const float*)d_in[10];
  const float* emb[3] = {(const float*)d_in[11], (const float*)d_in[12], (const float*)d_in[13]};
  const float* qkv_w = (const float*)d_in[14];
  const float* qkv_b = (const float*)d_in[15];
  const float* W_edge = (const float*)d_in[16];
  float* out = (float*)d_out;

  const int TYPE_N[3] = {NP, NU, NS};
  const int TYPE_OFF[3] = {0, NP, NP + NU};
  const int ET_SRC[3] = {1, 0, 2};
  const int ET_DST[3] = {0, 2, 1};
  const int ET_E[3] = {400000, 300000, 300000};

  char* ws = (char*)d_ws;
  size_t o = 0;
  auto carve = [&](size_t bytes) {
    char* p = ws + o;
    o = (o + bytes + 255) & ~(size_t)255;
    return p;
  };
  // node features, bf16 hi/lo, ping-pong (A = layer input, B = layer-0 output)
  ushort* XsAHi = (ushort*)carve((size_t)170000 * 128 * 2);
  ushort* XsALo = (ushort*)carve((size_t)170000 * 128 * 2);
  ushort* XsBHi = (ushort*)carve((size_t)170000 * 128 * 2);
  ushort* XsBLo = (ushort*)carve((size_t)170000 * 128 * 2);
  // Q|K pool (V overwrites Q after scores); max Ms+Md = 150000 rows
  float* qkpool = (float*)carve((size_t)150000 * 128 * 4);
  ushort* WtHi = (ushort*)carve((size_t)3 * 16384 * 2);  // [Q, V, Keff] transposed
  ushort* WtLo = (ushort*)carve((size_t)3 * 16384 * 2);
  float* Keff = (float*)carve(128 * 128 * 4);
  float* bkeff = (float*)carve(128 * 4);
  float* exb = (float*)carve(400000 * 4);
  float* den = (float*)carve(100000 * 4);
  int* cnt = (int*)carve(100000 * 4);
  int* bsums = (int*)carve(1024 * 4);
  int* rp[3];
  rp[0] = (int*)carve((NP + 1) * 4);
  rp[1] = (int*)carve((NS + 1) * 4);
  rp[2] = (int*)carve((NU + 1) * 4);
  int* eids[3];
  eids[0] = (int*)carve(400000 * 4);
  eids[1] = (int*)carve(300000 * 4);
  eids[2] = (int*)carve(300000 * 4);
  (void)ws_size;

  // ---- initial features (f32 compute, bf16 hi/lo store) ----
  for (int t = 0; t < 3; ++t) {
    k_init<<<TYPE_N[t], 128, 0, stream>>>(x_in[t], lin_w + t * 20 * 128, lin_b + t * 128,
                                          emb[t], nid[t],
                                          XsAHi + (size_t)TYPE_OFF[t] * 128,
                                          XsALo + (size_t)TYPE_OFF[t] * 128, TYPE_N[t]);
  }

  // ---- CSR per edge type (by destination) ----
  for (int et = 0; et < 3; ++et) {
    int E = ET_E[et];
    int Nd = TYPE_N[ET_DST[et]];
    const int* dstp = ei[et] + E;
    int nb = (Nd + 1023) / 1024;
    hipMemsetAsync(cnt, 0, (size_t)Nd * 4, stream);
    k_count<<<(E + 255) / 256, 256, 0, stream>>>(dstp, E, cnt);
    k_blocksum<<<nb, 256, 0, stream>>>(cnt, Nd, bsums);
    k_scan_bsums<<<1, 256, 0, stream>>>(bsums, nb);
    k_scan_apply<<<nb, 256, 0, stream>>>(cnt, bsums, rp[et], Nd);
    hipMemsetAsync(cnt, 0, (size_t)Nd * 4, stream);
    k_fill<<<(E + 255) / 256, 256, 0, stream>>>(dstp, E, rp[et], cnt, eids[et]);
  }

  const float scale = 0.08838834764831845f;  // 1/sqrt(128)

  for (int l = 0; l < 2; ++l) {
    const ushort* XinHi = (l == 0) ? XsAHi : XsBHi;
    const ushort* XinLo = (l == 0) ? XsALo : XsBLo;

    for (int et = 0; et < 3; ++et) {
      int st = ET_SRC[et], dt = ET_DST[et];
      int Ms = TYPE_N[st], Md = TYPE_N[dt];
      int E = ET_E[et];
      const float* Wq = qkv_w + (size_t)(((l * 3 + st) * 3 + 0)) * 16384;
      const float* bq = qkv_b + (size_t)(((l * 3 + st) * 3 + 0)) * 128;
      const float* Wk = qkv_w + (size_t)(((l * 3 + dt) * 3 + 1)) * 16384;
      const float* bk = qkv_b + (size_t)(((l * 3 + dt) * 3 + 1)) * 128;
      const float* bv = qkv_b + (size_t)(((l * 3 + st) * 3 + 2)) * 128;
      const float* We = W_edge + (size_t)(l * 3 + et) * 16384;

      float* Qb = qkpool;                         // [Ms,128]
      float* Kb = qkpool + (size_t)Ms * 128;      // [Md,128]
      float* Vb = qkpool;                         // reuses Q space after scores

      k_keff<<<128, 128, 0, stream>>>(Wk, bk, We, Keff, bkeff);

      // split+transpose weights: slot0=Q, slot1=V (stride 2*16384), slot2=Keff
      {
        dim3 g(64, 2);
        k_splitw<<<g, 256, 0, stream>>>(Wq, 2 * 16384, WtHi, WtLo, 16384);
        k_splitw<<<64, 256, 0, stream>>>(Keff, 0, WtHi + 2 * 16384, WtLo + 2 * 16384, 0);
      }

      const ushort* Ahi_s = XinHi + (size_t)TYPE_OFF[st] * 128;
      const ushort* Alo_s = XinLo + (size_t)TYPE_OFF[st] * 128;
      const ushort* Ahi_d = XinHi + (size_t)TYPE_OFF[dt] * 128;
      const ushort* Alo_d = XinLo + (size_t)TYPE_OFF[dt] * 128;

      k_gemm<<<(Ms + 63) / 64, 256, 0, stream>>>(Ahi_s, Alo_s, WtHi, WtLo, bq, Qb, Ms);
      k_gemm<<<(Md + 63) / 64, 256, 0, stream>>>(Ahi_d, Alo_d, WtHi + 2 * 16384,
                                                 WtLo + 2 * 16384, bkeff, Kb, Md);

      hipMemsetAsync(den, 0, (size_t)Md * 4, stream);
      k_scores<<<(E * 16 + 255) / 256, 256, 0, stream>>>(ei[et], E, Qb, Kb, exb, den, scale);

      // V gemm (overwrites Q slot — safe, scores already consumed Q)
      k_gemm<<<(Ms + 63) / 64, 256, 0, stream>>>(Ahi_s, Alo_s, WtHi + 16384, WtLo + 16384,
                                                 bv, Vb, Ms);

      if (l == 0) {
        k_aggregate<0><<<Md, 128, 0, stream>>>(ei[et], rp[et], eids[et], exb, den, Vb,
                                               XsBHi + (size_t)TYPE_OFF[dt] * 128,
                                               XsBLo + (size_t)TYPE_OFF[dt] * 128,
                                               (float*)nullptr);
      } else {
        k_aggregate<1><<<Md, 128, 0, stream>>>(ei[et], rp[et], eids[et], exb, den, Vb,
                                               (ushort*)nullptr, (ushort*)nullptr,
                                               out + (size_t)TYPE_OFF[dt] * 128);
      }
    }
  }
}

// Round 4
// 1029.168 us; speedup vs baseline: 1.8131x; 1.5554x over previous
//
#include <hip/hip_runtime.h>

#define NP 50000
#define NU 100000
#define NS 20000

typedef __attribute__((ext_vector_type(8))) short short8;
typedef __attribute__((ext_vector_type(4))) float f32x4;
typedef unsigned int uint32;

__device__ inline ushort f2bf(float f) {
  uint32 u = __float_as_uint(f);
  uint32 r = (u + 0x7FFF + ((u >> 16) & 1)) >> 16;
  return (ushort)r;
}
__device__ inline float bf2f(ushort h) { return __uint_as_float(((uint32)h) << 16); }

// ---------------------------------------------------------------------------
// init: s = x @ lin_w + lin_b + emb[node_id]; write bf16 hi/lo split
// ---------------------------------------------------------------------------
__global__ __launch_bounds__(128) void k_init(const float* __restrict__ x,
                                              const float* __restrict__ lw,
                                              const float* __restrict__ lb,
                                              const float* __restrict__ emb,
                                              const int* __restrict__ nid,
                                              ushort* __restrict__ hi,
                                              ushort* __restrict__ lo, int N) {
  int n = blockIdx.x;
  int d = threadIdx.x;
  if (n >= N) return;
  float s = lb[d];
#pragma unroll
  for (int j = 0; j < 20; ++j) s += x[n * 20 + j] * lw[j * 128 + d];
  s += emb[nid[n] * 128 + d];
  ushort h = f2bf(s);
  hi[n * 128 + d] = h;
  lo[n * 128 + d] = f2bf(s - bf2f(h));
}

// ---------------------------------------------------------------------------
// Keff[c][d] = sum_f Wk[c][f] * We[d][f];  bkeff[d] = sum_f bk[f]*We[d][f]
// ---------------------------------------------------------------------------
__global__ __launch_bounds__(128) void k_keff(const float* __restrict__ Wk,
                                              const float* __restrict__ bk,
                                              const float* __restrict__ We,
                                              float* __restrict__ Keff,
                                              float* __restrict__ bkeff) {
  __shared__ float Wes[128][65];
  int c = blockIdx.x, tid = threadIdx.x;
  float s = 0.f, t = 0.f;
  for (int f0 = 0; f0 < 128; f0 += 64) {
    __syncthreads();
    int fr = tid & 63, r0 = tid >> 6;
    for (int it = 0; it < 64; ++it) {
      int row = it * 2 + r0;
      Wes[row][fr] = We[row * 128 + f0 + fr];
    }
    __syncthreads();
#pragma unroll 16
    for (int fp = 0; fp < 64; ++fp) {
      s += Wk[c * 128 + f0 + fp] * Wes[tid][fp];
    }
    if (c == 0) {
      for (int fp = 0; fp < 64; ++fp) t += bk[f0 + fp] * Wes[tid][fp];
    }
  }
  Keff[c * 128 + tid] = s;
  if (c == 0) bkeff[tid] = t;
}

// ---------------------------------------------------------------------------
// split + transpose 128x128 f32 weight(s) -> Wt[n][k] hi/lo bf16
// grid.x = 64, 256 threads; grid.y selects weight
// ---------------------------------------------------------------------------
__global__ __launch_bounds__(256) void k_splitw(const float* __restrict__ W, int srcStride,
                                                ushort* __restrict__ hi,
                                                ushort* __restrict__ lo, int dstStride) {
  const float* src = W + (size_t)blockIdx.y * srcStride;
  ushort* h = hi + (size_t)blockIdx.y * dstStride;
  ushort* l = lo + (size_t)blockIdx.y * dstStride;
  int idx = blockIdx.x * 256 + threadIdx.x;  // 0..16383
  int n = idx >> 7, c = idx & 127;
  float f = src[c * 128 + n];
  ushort hb = f2bf(f);
  h[idx] = hb;
  l[idx] = f2bf(f - bf2f(hb));
}

// ---------------------------------------------------------------------------
// Triple-B MFMA GEMM: Yq/Yk/Yv[M,128](bf16) = A[M,128] @ {Wq,Wk,Wv}^T + bias
// A = hi(+lo) bf16 split; W slots: Whi/Wlo + {0,1,2}*16384 (pre-transposed)
// 256 threads = 4 waves; wave w -> cols 32w..+31; block -> 64 rows
// ---------------------------------------------------------------------------
template <int HASLO>
__global__ __launch_bounds__(256) void k_gemm3(
    const ushort* __restrict__ Ahi, const ushort* __restrict__ Alo,
    const ushort* __restrict__ Whi, const ushort* __restrict__ Wlo,
    const float* __restrict__ bq, const float* __restrict__ bk,
    const float* __restrict__ bv,
    ushort* __restrict__ Yq, ushort* __restrict__ Yk, ushort* __restrict__ Yv,
    int M) {
  int tid = threadIdx.x;
  int wave = tid >> 6, lane = tid & 63;
  int row0 = blockIdx.x * 64;
  int colw = wave * 32;
  int lrow = lane & 15, kgrp = lane >> 4;

  f32x4 acc[3][4][2] = {};

  int rows[4];
#pragma unroll
  for (int mt = 0; mt < 4; ++mt) {
    int r = row0 + mt * 16 + lrow;
    rows[mt] = (r < M) ? r : (M - 1);
  }

#pragma unroll
  for (int s = 0; s < 4; ++s) {
    int koff = s * 32 + kgrp * 8;
    short8 ah[4], al[4];
#pragma unroll
    for (int mt = 0; mt < 4; ++mt) {
      ah[mt] = *(const short8*)(Ahi + (size_t)rows[mt] * 128 + koff);
      if (HASLO) al[mt] = *(const short8*)(Alo + (size_t)rows[mt] * 128 + koff);
    }
#pragma unroll
    for (int bw = 0; bw < 3; ++bw) {
      const ushort* Bh = Whi + bw * 16384;
      const ushort* Bl = Wlo + bw * 16384;
      short8 bh[2], bl[2];
#pragma unroll
      for (int nt = 0; nt < 2; ++nt) {
        int col = colw + nt * 16 + lrow;
        bh[nt] = *(const short8*)(Bh + col * 128 + koff);
        bl[nt] = *(const short8*)(Bl + col * 128 + koff);
      }
#pragma unroll
      for (int mt = 0; mt < 4; ++mt)
#pragma unroll
        for (int nt = 0; nt < 2; ++nt) {
          acc[bw][mt][nt] =
              __builtin_amdgcn_mfma_f32_16x16x32_bf16(ah[mt], bh[nt], acc[bw][mt][nt], 0, 0, 0);
          acc[bw][mt][nt] =
              __builtin_amdgcn_mfma_f32_16x16x32_bf16(ah[mt], bl[nt], acc[bw][mt][nt], 0, 0, 0);
          if (HASLO)
            acc[bw][mt][nt] =
                __builtin_amdgcn_mfma_f32_16x16x32_bf16(al[mt], bh[nt], acc[bw][mt][nt], 0, 0, 0);
        }
    }
  }

#pragma unroll
  for (int bw = 0; bw < 3; ++bw) {
    const float* bias = (bw == 0) ? bq : (bw == 1) ? bk : bv;
    ushort* Y = (bw == 0) ? Yq : (bw == 1) ? Yk : Yv;
#pragma unroll
    for (int mt = 0; mt < 4; ++mt) {
#pragma unroll
      for (int r = 0; r < 4; ++r) {
        int row = row0 + mt * 16 + kgrp * 4 + r;
        if (row < M) {
#pragma unroll
          for (int nt = 0; nt < 2; ++nt) {
            int col = colw + nt * 16 + lrow;
            Y[(size_t)row * 128 + col] = f2bf(acc[bw][mt][nt][r] + bias[col]);
          }
        }
      }
    }
  }
}

// ---------------------------------------------------------------------------
// CSR-ordered edge scores: one wave per dst node; 4 edge-slots x 16 lanes.
// K[dst] loaded once, reused across edges. den accumulated in registers.
// ---------------------------------------------------------------------------
__global__ __launch_bounds__(256) void k_scores_csr(
    const int* __restrict__ rowptr, const int* __restrict__ srcs,
    const ushort* __restrict__ Q, const ushort* __restrict__ K,
    float* __restrict__ ex, float* __restrict__ den, float scale, int Nd) {
  int wid = (blockIdx.x * 256 + threadIdx.x) >> 6;
  if (wid >= Nd) return;
  int lane = threadIdx.x & 63;
  int sub = lane & 15, eslot = lane >> 4;
  int s0 = rowptr[wid], s1 = rowptr[wid + 1];

  float kf[8];
  {
    short8 kv = *(const short8*)(K + (size_t)wid * 128 + sub * 8);
#pragma unroll
    for (int j = 0; j < 8; ++j) kf[j] = bf2f((ushort)kv[j]);
  }

  float dpart = 0.f;
  for (int k = s0 + eslot; k < s1; k += 4) {
    int src = srcs[k];
    short8 qv = *(const short8*)(Q + (size_t)src * 128 + sub * 8);
    float p = 0.f;
#pragma unroll
    for (int j = 0; j < 8; ++j) p += bf2f((ushort)qv[j]) * kf[j];
    p += __shfl_xor(p, 8, 16);
    p += __shfl_xor(p, 4, 16);
    p += __shfl_xor(p, 2, 16);
    p += __shfl_xor(p, 1, 16);
    float s = p * scale;
    s = (s > 0.f) ? s : 0.01f * s;
    float v = __expf(s);
    if (sub == 0) {
      ex[k] = v;
      dpart += v;
    }
  }
  dpart += __shfl_xor(dpart, 16, 64);
  dpart += __shfl_xor(dpart, 32, 64);
  if (lane == 0) den[wid] = dpart;
}

// ---------------------------------------------------------------------------
// CSR build: count -> hierarchical scan -> fill (srcs in CSR slot order)
// ---------------------------------------------------------------------------
__global__ void k_count(const int* __restrict__ dst, int E, int* __restrict__ counts) {
  int e = blockIdx.x * 256 + threadIdx.x;
  if (e < E) atomicAdd(&counts[dst[e]], 1);
}

__global__ __launch_bounds__(256) void k_blocksum(const int* __restrict__ c, int N,
                                                  int* __restrict__ bs) {
  int base = blockIdx.x * 1024;
  int t = threadIdx.x;
  int s = 0;
#pragma unroll
  for (int j = 0; j < 4; ++j) {
    int i = base + t * 4 + j;
    if (i < N) s += c[i];
  }
#pragma unroll
  for (int off = 32; off; off >>= 1) s += __shfl_down(s, off, 64);
  __shared__ int wsm[4];
  if ((t & 63) == 0) wsm[t >> 6] = s;
  __syncthreads();
  if (t == 0) bs[blockIdx.x] = wsm[0] + wsm[1] + wsm[2] + wsm[3];
}

__global__ __launch_bounds__(256) void k_scan_bsums(int* __restrict__ bs, int nb) {
  __shared__ int sm[256];
  int t = threadIdx.x;
  int v[4];
  int s = 0;
#pragma unroll
  for (int j = 0; j < 4; ++j) {
    int i = t * 4 + j;
    v[j] = (i < nb) ? bs[i] : 0;
    s += v[j];
  }
  sm[t] = s;
  __syncthreads();
  for (int off = 1; off < 256; off <<= 1) {
    int x = (t >= off) ? sm[t - off] : 0;
    __syncthreads();
    sm[t] += x;
    __syncthreads();
  }
  int run = t ? sm[t - 1] : 0;
#pragma unroll
  for (int j = 0; j < 4; ++j) {
    int i = t * 4 + j;
    if (i < nb) {
      int tmp = v[j];
      bs[i] = run;
      run += tmp;
    }
  }
}

__global__ __launch_bounds__(256) void k_scan_apply(const int* __restrict__ c,
                                                    const int* __restrict__ bofs,
                                                    int* __restrict__ rowptr, int N) {
  __shared__ int sm[256];
  int base = blockIdx.x * 1024, t = threadIdx.x;
  int v[4];
  int s = 0;
#pragma unroll
  for (int j = 0; j < 4; ++j) {
    int i = base + t * 4 + j;
    v[j] = (i < N) ? c[i] : 0;
    s += v[j];
  }
  sm[t] = s;
  __syncthreads();
  for (int off = 1; off < 256; off <<= 1) {
    int x = (t >= off) ? sm[t - off] : 0;
    __syncthreads();
    sm[t] += x;
    __syncthreads();
  }
  int run = bofs[blockIdx.x] + (t ? sm[t - 1] : 0);
#pragma unroll
  for (int j = 0; j < 4; ++j) {
    int i = base + t * 4 + j;
    if (i < N) {
      run += v[j];
      rowptr[i + 1] = run;
    }
  }
  if (blockIdx.x == 0 && t == 0) rowptr[0] = 0;
}

__global__ void k_fill(const int* __restrict__ ei, int E,
                       const int* __restrict__ rowptr, int* __restrict__ cursor,
                       int* __restrict__ srcs) {
  int e = blockIdx.x * 256 + threadIdx.x;
  if (e < E) {
    int s = ei[e];
    int d = ei[E + e];
    int p = atomicAdd(&cursor[d], 1);
    srcs[rowptr[d] + p] = s;
  }
}

// ---------------------------------------------------------------------------
// CSR aggregate: one wave per dst; lane handles 2 dims (ushort2 V loads).
// MODE 0 -> relu + write bf16; MODE 1 -> write f32 (final output)
// ---------------------------------------------------------------------------
template <int MODE>
__global__ __launch_bounds__(256) void k_agg_csr(
    const int* __restrict__ rowptr, const int* __restrict__ srcs,
    const float* __restrict__ ex, const float* __restrict__ den,
    const ushort* __restrict__ V, ushort* __restrict__ obf,
    float* __restrict__ of, int Nd) {
  int wid = (blockIdx.x * 256 + threadIdx.x) >> 6;
  if (wid >= Nd) return;
  int lane = threadIdx.x & 63;
  int s0 = rowptr[wid], s1 = rowptr[wid + 1];
  float inv = (s1 > s0) ? 1.f / den[wid] : 0.f;
  float a0 = 0.f, a1 = 0.f;
  int k = s0;
  for (; k + 1 < s1; k += 2) {
    int src0 = srcs[k], src1 = srcs[k + 1];
    float w0 = ex[k], w1 = ex[k + 1];
    uint32 v0 = *(const uint32*)(V + (size_t)src0 * 128 + lane * 2);
    uint32 v1 = *(const uint32*)(V + (size_t)src1 * 128 + lane * 2);
    a0 += w0 * bf2f((ushort)(v0 & 0xffff)) + w1 * bf2f((ushort)(v1 & 0xffff));
    a1 += w0 * bf2f((ushort)(v0 >> 16)) + w1 * bf2f((ushort)(v1 >> 16));
  }
  if (k < s1) {
    int src0 = srcs[k];
    float w0 = ex[k];
    uint32 v0 = *(const uint32*)(V + (size_t)src0 * 128 + lane * 2);
    a0 += w0 * bf2f((ushort)(v0 & 0xffff));
    a1 += w0 * bf2f((ushort)(v0 >> 16));
  }
  a0 *= inv;
  a1 *= inv;
  if (MODE == 0) {
    a0 = fmaxf(a0, 0.f);
    a1 = fmaxf(a1, 0.f);
    uint32 o = (uint32)f2bf(a0) | ((uint32)f2bf(a1) << 16);
    *(uint32*)(obf + (size_t)wid * 128 + lane * 2) = o;
  } else {
    float2 o = make_float2(a0, a1);
    *(float2*)(of + (size_t)wid * 128 + lane * 2) = o;
  }
}

// ---------------------------------------------------------------------------

extern "C" void kernel_launch(void* const* d_in, const int* in_sizes, int n_in,
                              void* d_out, int out_size, void* d_ws, size_t ws_size,
                              hipStream_t stream) {
  const float* x_in[3] = {(const float*)d_in[0], (const float*)d_in[1], (const float*)d_in[2]};
  const int* nid[3] = {(const int*)d_in[3], (const int*)d_in[4], (const int*)d_in[5]};
  const int* ei[3] = {(const int*)d_in[6], (const int*)d_in[7], (const int*)d_in[8]};
  const float* lin_w = (const float*)d_in[9];
  const float* lin_b = (const float*)d_in[10];
  const float* emb[3] = {(const float*)d_in[11], (const float*)d_in[12], (const float*)d_in[13]};
  const float* qkv_w = (const float*)d_in[14];
  const float* qkv_b = (const float*)d_in[15];
  const float* W_edge = (const float*)d_in[16];
  float* out = (float*)d_out;

  const int TYPE_N[3] = {NP, NU, NS};
  const int TYPE_OFF[3] = {0, NP, NP + NU};
  const int ET_SRC[3] = {1, 0, 2};
  const int ET_DST[3] = {0, 2, 1};
  const int ET_E[3] = {400000, 300000, 300000};
  const int ET_OF_DSTTYPE[3] = {0, 2, 1};  // type t is dst of this edge type

  char* ws = (char*)d_ws;
  size_t o = 0;
  auto carve = [&](size_t bytes) {
    char* p = ws + o;
    o = (o + bytes + 255) & ~(size_t)255;
    return p;
  };
  // node features: layer-1 input hi/lo, layer-2 input single bf16
  ushort* XsAHi = (ushort*)carve((size_t)170000 * 128 * 2);
  ushort* XsALo = (ushort*)carve((size_t)170000 * 128 * 2);
  ushort* XsB = (ushort*)carve((size_t)170000 * 128 * 2);
  // per-type Q/K/V (bf16), full 170000 rows each
  ushort* Qb = (ushort*)carve((size_t)170000 * 128 * 2);
  ushort* Kb = (ushort*)carve((size_t)170000 * 128 * 2);
  ushort* Vb = (ushort*)carve((size_t)170000 * 128 * 2);
  float* Keff3 = (float*)carve(3 * 16384 * 4);
  float* bkeff3 = (float*)carve(3 * 128 * 4);
  ushort* WtHi = (ushort*)carve((size_t)9 * 16384 * 2);  // [type][{Q,K,V}]
  ushort* WtLo = (ushort*)carve((size_t)9 * 16384 * 2);
  float* exb = (float*)carve(400000 * 4);
  float* den = (float*)carve(100000 * 4);
  int* cnt = (int*)carve(100000 * 4);
  int* bsums = (int*)carve(1024 * 4);
  int* rp[3];
  rp[0] = (int*)carve((NP + 1) * 4);
  rp[1] = (int*)carve((NS + 1) * 4);
  rp[2] = (int*)carve((NU + 1) * 4);
  int* srcs[3];
  srcs[0] = (int*)carve(400000 * 4);
  srcs[1] = (int*)carve(300000 * 4);
  srcs[2] = (int*)carve(300000 * 4);
  (void)ws_size;

  // ---- initial features ----
  for (int t = 0; t < 3; ++t) {
    k_init<<<TYPE_N[t], 128, 0, stream>>>(x_in[t], lin_w + t * 20 * 128, lin_b + t * 128,
                                          emb[t], nid[t],
                                          XsAHi + (size_t)TYPE_OFF[t] * 128,
                                          XsALo + (size_t)TYPE_OFF[t] * 128, TYPE_N[t]);
  }

  // ---- CSR per edge type (by destination), srcs in slot order ----
  for (int et = 0; et < 3; ++et) {
    int E = ET_E[et];
    int Nd = TYPE_N[ET_DST[et]];
    const int* dstp = ei[et] + E;
    int nb = (Nd + 1023) / 1024;
    hipMemsetAsync(cnt, 0, (size_t)Nd * 4, stream);
    k_count<<<(E + 255) / 256, 256, 0, stream>>>(dstp, E, cnt);
    k_blocksum<<<nb, 256, 0, stream>>>(cnt, Nd, bsums);
    k_scan_bsums<<<1, 256, 0, stream>>>(bsums, nb);
    k_scan_apply<<<nb, 256, 0, stream>>>(cnt, bsums, rp[et], Nd);
    hipMemsetAsync(cnt, 0, (size_t)Nd * 4, stream);
    k_fill<<<(E + 255) / 256, 256, 0, stream>>>(ei[et], E, rp[et], cnt, srcs[et]);
  }

  const float scale = 0.08838834764831845f;  // 1/sqrt(128)

  for (int l = 0; l < 2; ++l) {
    const ushort* XinHi = (l == 0) ? XsAHi : XsB;
    const ushort* XinLo = XsALo;  // only used when l==0

    // ---- per-type weight prep: Keff per type, then split+transpose all ----
    for (int t = 0; t < 3; ++t) {
      int et = ET_OF_DSTTYPE[t];
      const float* Wk = qkv_w + (size_t)((l * 3 + t) * 3 + 1) * 16384;
      const float* bk = qkv_b + (size_t)((l * 3 + t) * 3 + 1) * 128;
      const float* We = W_edge + (size_t)(l * 3 + et) * 16384;
      k_keff<<<128, 128, 0, stream>>>(Wk, bk, We, Keff3 + t * 16384, bkeff3 + t * 128);
    }
    {
      dim3 g(64, 3);
      // Q weights -> slots t*3+0
      k_splitw<<<g, 256, 0, stream>>>(qkv_w + (size_t)(9 * l) * 16384, 3 * 16384,
                                      WtHi, WtLo, 3 * 16384);
      // Keff -> slots t*3+1
      k_splitw<<<g, 256, 0, stream>>>(Keff3, 16384, WtHi + 16384, WtLo + 16384, 3 * 16384);
      // V weights -> slots t*3+2
      k_splitw<<<g, 256, 0, stream>>>(qkv_w + (size_t)(9 * l + 2) * 16384, 3 * 16384,
                                      WtHi + 2 * 16384, WtLo + 2 * 16384, 3 * 16384);
    }

    // ---- per-type fused Q/K/V GEMM ----
    for (int t = 0; t < 3; ++t) {
      int N = TYPE_N[t];
      size_t off = (size_t)TYPE_OFF[t] * 128;
      const float* bq = qkv_b + (size_t)((l * 3 + t) * 3 + 0) * 128;
      const float* bv = qkv_b + (size_t)((l * 3 + t) * 3 + 2) * 128;
      if (l == 0)
        k_gemm3<1><<<(N + 63) / 64, 256, 0, stream>>>(
            XinHi + off, XinLo + off, WtHi + (size_t)t * 3 * 16384,
            WtLo + (size_t)t * 3 * 16384, bq, bkeff3 + t * 128, bv,
            Qb + off, Kb + off, Vb + off, N);
      else
        k_gemm3<0><<<(N + 63) / 64, 256, 0, stream>>>(
            XinHi + off, XinHi + off, WtHi + (size_t)t * 3 * 16384,
            WtLo + (size_t)t * 3 * 16384, bq, bkeff3 + t * 128, bv,
            Qb + off, Kb + off, Vb + off, N);
    }

    // ---- per-edge-type scores + aggregate ----
    for (int et = 0; et < 3; ++et) {
      int st = ET_SRC[et], dt = ET_DST[et];
      int Nd = TYPE_N[dt];
      size_t offs = (size_t)TYPE_OFF[st] * 128;
      size_t offd = (size_t)TYPE_OFF[dt] * 128;
      int grid = (Nd + 3) / 4;
      k_scores_csr<<<grid, 256, 0, stream>>>(rp[et], srcs[et], Qb + offs, Kb + offd,
                                             exb, den, scale, Nd);
      if (l == 0)
        k_agg_csr<0><<<grid, 256, 0, stream>>>(rp[et], srcs[et], exb, den, Vb + offs,
                                               XsB + offd, (float*)nullptr, Nd);
      else
        k_agg_csr<1><<<grid, 256, 0, stream>>>(rp[et], srcs[et], exb, den, Vb + offs,
                                               (ushort*)nullptr, out + offd, Nd);
    }
  }
}

// Round 5
// 991.718 us; speedup vs baseline: 1.8816x; 1.0378x over previous
//
#include <hip/hip_runtime.h>

#define NP 50000
#define NU 100000
#define NS 20000

typedef __attribute__((ext_vector_type(8))) short short8;
typedef __attribute__((ext_vector_type(4))) float f32x4;
typedef unsigned int uint32;

__device__ inline ushort f2bf(float f) {
  uint32 u = __float_as_uint(f);
  uint32 r = (u + 0x7FFF + ((u >> 16) & 1)) >> 16;
  return (ushort)r;
}
__device__ inline float bf2f(ushort h) { return __uint_as_float(((uint32)h) << 16); }

// ---------------------------------------------------------------------------
// init: s = x @ lin_w + lin_b + emb[node_id]; write bf16
// ---------------------------------------------------------------------------
__global__ __launch_bounds__(128) void k_init(const float* __restrict__ x,
                                              const float* __restrict__ lw,
                                              const float* __restrict__ lb,
                                              const float* __restrict__ emb,
                                              const int* __restrict__ nid,
                                              ushort* __restrict__ xb, int N) {
  int n = blockIdx.x;
  int d = threadIdx.x;
  if (n >= N) return;
  float s = lb[d];
#pragma unroll
  for (int j = 0; j < 20; ++j) s += x[n * 20 + j] * lw[j * 128 + d];
  s += emb[nid[n] * 128 + d];
  xb[n * 128 + d] = f2bf(s);
}

// ---------------------------------------------------------------------------
// Keff[c][d] = sum_f Wk[c][f] * We[d][f];  bkeff[d] = sum_f bk[f]*We[d][f]
// ---------------------------------------------------------------------------
__global__ __launch_bounds__(128) void k_keff(const float* __restrict__ Wk,
                                              const float* __restrict__ bk,
                                              const float* __restrict__ We,
                                              float* __restrict__ Keff,
                                              float* __restrict__ bkeff) {
  __shared__ float Wes[128][65];
  int c = blockIdx.x, tid = threadIdx.x;
  float s = 0.f, t = 0.f;
  for (int f0 = 0; f0 < 128; f0 += 64) {
    __syncthreads();
    int fr = tid & 63, r0 = tid >> 6;
    for (int it = 0; it < 64; ++it) {
      int row = it * 2 + r0;
      Wes[row][fr] = We[row * 128 + f0 + fr];
    }
    __syncthreads();
#pragma unroll 16
    for (int fp = 0; fp < 64; ++fp) {
      s += Wk[c * 128 + f0 + fp] * Wes[tid][fp];
    }
    if (c == 0) {
      for (int fp = 0; fp < 64; ++fp) t += bk[f0 + fp] * Wes[tid][fp];
    }
  }
  Keff[c * 128 + tid] = s;
  if (c == 0) bkeff[tid] = t;
}

// ---------------------------------------------------------------------------
// split + transpose 128x128 f32 weight(s) -> Wt[n][k] hi/lo bf16
// ---------------------------------------------------------------------------
__global__ __launch_bounds__(256) void k_splitw(const float* __restrict__ W, int srcStride,
                                                ushort* __restrict__ hi,
                                                ushort* __restrict__ lo, int dstStride) {
  const float* src = W + (size_t)blockIdx.y * srcStride;
  ushort* h = hi + (size_t)blockIdx.y * dstStride;
  ushort* l = lo + (size_t)blockIdx.y * dstStride;
  int idx = blockIdx.x * 256 + threadIdx.x;  // 0..16383
  int n = idx >> 7, c = idx & 127;
  float f = src[c * 128 + n];
  ushort hb = f2bf(f);
  h[idx] = hb;
  l[idx] = f2bf(f - bf2f(hb));
}

// ---------------------------------------------------------------------------
// Triple-B MFMA GEMM v2: Yq/Yk/Yv[M,128](bf16) = A[M,128](bf16) @ W^T + bias
// BM=128 staged once in LDS (XOR-swizzled chunks, G4); bw outer loop reuses
// acc[8][2] (64 VGPR); W hi/lo (2 MFMA terms); 4 waves, wave=32 cols.
// ---------------------------------------------------------------------------
__global__ __launch_bounds__(256, 4) void k_gemm3(
    const ushort* __restrict__ A,
    const ushort* __restrict__ Whi, const ushort* __restrict__ Wlo,
    const float* __restrict__ bq, const float* __restrict__ bk,
    const float* __restrict__ bv,
    ushort* __restrict__ Yq, ushort* __restrict__ Yk, ushort* __restrict__ Yv,
    int M) {
  __shared__ ushort As[128 * 128];  // 32 KB
  int tid = threadIdx.x;
  int wave = tid >> 6, lane = tid & 63;
  int row0 = blockIdx.x * 128;
  int colw = wave * 32;
  int lrow = lane & 15, kgrp = lane >> 4;

  // ---- stage A tile: linear global read, swizzled LDS write ----
#pragma unroll
  for (int i = 0; i < 8; ++i) {
    int chunkLin = i * 256 + tid;  // 16B chunk id, 0..2047
    int row = chunkLin >> 4;
    int chunk = chunkLin & 15;
    int grow = row0 + row;
    if (grow >= M) grow = M - 1;
    short8 v = *(const short8*)(A + (size_t)grow * 128 + chunk * 8);
    int c2 = chunk ^ (row & 7);
    *(short8*)(As + row * 128 + c2 * 8) = v;
  }
  __syncthreads();

  int x7 = lrow & 7;

#pragma unroll
  for (int bw = 0; bw < 3; ++bw) {
    f32x4 acc[8][2] = {};
#pragma unroll
    for (int s = 0; s < 4; ++s) {
      short8 bh[2], bl[2];
#pragma unroll
      for (int nt = 0; nt < 2; ++nt) {
        int col = colw + nt * 16 + lrow;
        size_t boff = (size_t)bw * 16384 + col * 128 + s * 32 + kgrp * 8;
        bh[nt] = *(const short8*)(Whi + boff);
        bl[nt] = *(const short8*)(Wlo + boff);
      }
      int c2 = (s * 4 + kgrp) ^ x7;
#pragma unroll
      for (int mt = 0; mt < 8; ++mt) {
        int row = mt * 16 + lrow;
        short8 a = *(const short8*)(As + row * 128 + c2 * 8);
        acc[mt][0] = __builtin_amdgcn_mfma_f32_16x16x32_bf16(a, bh[0], acc[mt][0], 0, 0, 0);
        acc[mt][0] = __builtin_amdgcn_mfma_f32_16x16x32_bf16(a, bl[0], acc[mt][0], 0, 0, 0);
        acc[mt][1] = __builtin_amdgcn_mfma_f32_16x16x32_bf16(a, bh[1], acc[mt][1], 0, 0, 0);
        acc[mt][1] = __builtin_amdgcn_mfma_f32_16x16x32_bf16(a, bl[1], acc[mt][1], 0, 0, 0);
      }
    }
    // ---- epilogue for this weight ----
    const float* bias = (bw == 0) ? bq : (bw == 1) ? bk : bv;
    ushort* Y = (bw == 0) ? Yq : (bw == 1) ? Yk : Yv;
    float b0 = bias[colw + lrow];
    float b1 = bias[colw + 16 + lrow];
#pragma unroll
    for (int mt = 0; mt < 8; ++mt) {
#pragma unroll
      for (int r = 0; r < 4; ++r) {
        int row = row0 + mt * 16 + kgrp * 4 + r;
        if (row < M) {
          Y[(size_t)row * 128 + colw + lrow] = f2bf(acc[mt][0][r] + b0);
          Y[(size_t)row * 128 + colw + 16 + lrow] = f2bf(acc[mt][1][r] + b1);
        }
      }
    }
  }
}

// ---------------------------------------------------------------------------
// CSR-ordered edge scores: one wave per dst node; 4 edge-slots x 16 lanes.
// ---------------------------------------------------------------------------
__global__ __launch_bounds__(256) void k_scores_csr(
    const int* __restrict__ rowptr, const int* __restrict__ srcs,
    const ushort* __restrict__ Q, const ushort* __restrict__ K,
    float* __restrict__ ex, float* __restrict__ den, float scale, int Nd) {
  int wid = (blockIdx.x * 256 + threadIdx.x) >> 6;
  if (wid >= Nd) return;
  int lane = threadIdx.x & 63;
  int sub = lane & 15, eslot = lane >> 4;
  int s0 = rowptr[wid], s1 = rowptr[wid + 1];

  float kf[8];
  {
    short8 kv = *(const short8*)(K + (size_t)wid * 128 + sub * 8);
#pragma unroll
    for (int j = 0; j < 8; ++j) kf[j] = bf2f((ushort)kv[j]);
  }

  float dpart = 0.f;
  for (int k = s0 + eslot; k < s1; k += 4) {
    int src = srcs[k];
    short8 qv = *(const short8*)(Q + (size_t)src * 128 + sub * 8);
    float p = 0.f;
#pragma unroll
    for (int j = 0; j < 8; ++j) p += bf2f((ushort)qv[j]) * kf[j];
    p += __shfl_xor(p, 8, 16);
    p += __shfl_xor(p, 4, 16);
    p += __shfl_xor(p, 2, 16);
    p += __shfl_xor(p, 1, 16);
    float s = p * scale;
    s = (s > 0.f) ? s : 0.01f * s;
    float v = __expf(s);
    if (sub == 0) {
      ex[k] = v;
      dpart += v;
    }
  }
  dpart += __shfl_xor(dpart, 16, 64);
  dpart += __shfl_xor(dpart, 32, 64);
  if (lane == 0) den[wid] = dpart;
}

// ---------------------------------------------------------------------------
// CSR build: count -> hierarchical scan -> fill
// ---------------------------------------------------------------------------
__global__ void k_count(const int* __restrict__ dst, int E, int* __restrict__ counts) {
  int e = blockIdx.x * 256 + threadIdx.x;
  if (e < E) atomicAdd(&counts[dst[e]], 1);
}

__global__ __launch_bounds__(256) void k_blocksum(const int* __restrict__ c, int N,
                                                  int* __restrict__ bs) {
  int base = blockIdx.x * 1024;
  int t = threadIdx.x;
  int s = 0;
#pragma unroll
  for (int j = 0; j < 4; ++j) {
    int i = base + t * 4 + j;
    if (i < N) s += c[i];
  }
#pragma unroll
  for (int off = 32; off; off >>= 1) s += __shfl_down(s, off, 64);
  __shared__ int wsm[4];
  if ((t & 63) == 0) wsm[t >> 6] = s;
  __syncthreads();
  if (t == 0) bs[blockIdx.x] = wsm[0] + wsm[1] + wsm[2] + wsm[3];
}

__global__ __launch_bounds__(256) void k_scan_bsums(int* __restrict__ bs, int nb) {
  __shared__ int sm[256];
  int t = threadIdx.x;
  int v[4];
  int s = 0;
#pragma unroll
  for (int j = 0; j < 4; ++j) {
    int i = t * 4 + j;
    v[j] = (i < nb) ? bs[i] : 0;
    s += v[j];
  }
  sm[t] = s;
  __syncthreads();
  for (int off = 1; off < 256; off <<= 1) {
    int x = (t >= off) ? sm[t - off] : 0;
    __syncthreads();
    sm[t] += x;
    __syncthreads();
  }
  int run = t ? sm[t - 1] : 0;
#pragma unroll
  for (int j = 0; j < 4; ++j) {
    int i = t * 4 + j;
    if (i < nb) {
      int tmp = v[j];
      bs[i] = run;
      run += tmp;
    }
  }
}

__global__ __launch_bounds__(256) void k_scan_apply(const int* __restrict__ c,
                                                    const int* __restrict__ bofs,
                                                    int* __restrict__ rowptr, int N) {
  __shared__ int sm[256];
  int base = blockIdx.x * 1024, t = threadIdx.x;
  int v[4];
  int s = 0;
#pragma unroll
  for (int j = 0; j < 4; ++j) {
    int i = base + t * 4 + j;
    v[j] = (i < N) ? c[i] : 0;
    s += v[j];
  }
  sm[t] = s;
  __syncthreads();
  for (int off = 1; off < 256; off <<= 1) {
    int x = (t >= off) ? sm[t - off] : 0;
    __syncthreads();
    sm[t] += x;
    __syncthreads();
  }
  int run = bofs[blockIdx.x] + (t ? sm[t - 1] : 0);
#pragma unroll
  for (int j = 0; j < 4; ++j) {
    int i = base + t * 4 + j;
    if (i < N) {
      run += v[j];
      rowptr[i + 1] = run;
    }
  }
  if (blockIdx.x == 0 && t == 0) rowptr[0] = 0;
}

__global__ void k_fill(const int* __restrict__ ei, int E,
                       const int* __restrict__ rowptr, int* __restrict__ cursor,
                       int* __restrict__ srcs) {
  int e = blockIdx.x * 256 + threadIdx.x;
  if (e < E) {
    int s = ei[e];
    int d = ei[E + e];
    int p = atomicAdd(&cursor[d], 1);
    srcs[rowptr[d] + p] = s;
  }
}

// ---------------------------------------------------------------------------
// CSR aggregate: one wave per dst; lane handles 2 dims.
// MODE 0 -> relu + write bf16; MODE 1 -> write f32 (final output)
// ---------------------------------------------------------------------------
template <int MODE>
__global__ __launch_bounds__(256) void k_agg_csr(
    const int* __restrict__ rowptr, const int* __restrict__ srcs,
    const float* __restrict__ ex, const float* __restrict__ den,
    const ushort* __restrict__ V, ushort* __restrict__ obf,
    float* __restrict__ of, int Nd) {
  int wid = (blockIdx.x * 256 + threadIdx.x) >> 6;
  if (wid >= Nd) return;
  int lane = threadIdx.x & 63;
  int s0 = rowptr[wid], s1 = rowptr[wid + 1];
  float inv = (s1 > s0) ? 1.f / den[wid] : 0.f;
  float a0 = 0.f, a1 = 0.f;
  int k = s0;
  for (; k + 1 < s1; k += 2) {
    int src0 = srcs[k], src1 = srcs[k + 1];
    float w0 = ex[k], w1 = ex[k + 1];
    uint32 v0 = *(const uint32*)(V + (size_t)src0 * 128 + lane * 2);
    uint32 v1 = *(const uint32*)(V + (size_t)src1 * 128 + lane * 2);
    a0 += w0 * bf2f((ushort)(v0 & 0xffff)) + w1 * bf2f((ushort)(v1 & 0xffff));
    a1 += w0 * bf2f((ushort)(v0 >> 16)) + w1 * bf2f((ushort)(v1 >> 16));
  }
  if (k < s1) {
    int src0 = srcs[k];
    float w0 = ex[k];
    uint32 v0 = *(const uint32*)(V + (size_t)src0 * 128 + lane * 2);
    a0 += w0 * bf2f((ushort)(v0 & 0xffff));
    a1 += w0 * bf2f((ushort)(v0 >> 16));
  }
  a0 *= inv;
  a1 *= inv;
  if (MODE == 0) {
    a0 = fmaxf(a0, 0.f);
    a1 = fmaxf(a1, 0.f);
    uint32 o = (uint32)f2bf(a0) | ((uint32)f2bf(a1) << 16);
    *(uint32*)(obf + (size_t)wid * 128 + lane * 2) = o;
  } else {
    float2 o = make_float2(a0, a1);
    *(float2*)(of + (size_t)wid * 128 + lane * 2) = o;
  }
}

// ---------------------------------------------------------------------------

extern "C" void kernel_launch(void* const* d_in, const int* in_sizes, int n_in,
                              void* d_out, int out_size, void* d_ws, size_t ws_size,
                              hipStream_t stream) {
  const float* x_in[3] = {(const float*)d_in[0], (const float*)d_in[1], (const float*)d_in[2]};
  const int* nid[3] = {(const int*)d_in[3], (const int*)d_in[4], (const int*)d_in[5]};
  const int* ei[3] = {(const int*)d_in[6], (const int*)d_in[7], (const int*)d_in[8]};
  const float* lin_w = (const float*)d_in[9];
  const float* lin_b = (const float*)d_in[10];
  const float* emb[3] = {(const float*)d_in[11], (const float*)d_in[12], (const float*)d_in[13]};
  const float* qkv_w = (const float*)d_in[14];
  const float* qkv_b = (const float*)d_in[15];
  const float* W_edge = (const float*)d_in[16];
  float* out = (float*)d_out;

  const int TYPE_N[3] = {NP, NU, NS};
  const int TYPE_OFF[3] = {0, NP, NP + NU};
  const int ET_SRC[3] = {1, 0, 2};
  const int ET_DST[3] = {0, 2, 1};
  const int ET_E[3] = {400000, 300000, 300000};
  const int ET_OF_DSTTYPE[3] = {0, 2, 1};  // edge type for which type t is dst

  char* ws = (char*)d_ws;
  size_t o = 0;
  auto carve = [&](size_t bytes) {
    char* p = ws + o;
    o = (o + bytes + 255) & ~(size_t)255;
    return p;
  };
  ushort* XsA = (ushort*)carve((size_t)170000 * 128 * 2);
  ushort* XsB = (ushort*)carve((size_t)170000 * 128 * 2);
  ushort* Qb = (ushort*)carve((size_t)170000 * 128 * 2);
  ushort* Kb = (ushort*)carve((size_t)170000 * 128 * 2);
  ushort* Vb = (ushort*)carve((size_t)170000 * 128 * 2);
  float* Keff3 = (float*)carve(3 * 16384 * 4);
  float* bkeff3 = (float*)carve(3 * 128 * 4);
  ushort* WtHi = (ushort*)carve((size_t)9 * 16384 * 2);  // [type][{Q,K,V}]
  ushort* WtLo = (ushort*)carve((size_t)9 * 16384 * 2);
  float* exb = (float*)carve(400000 * 4);
  float* den = (float*)carve(100000 * 4);
  int* cnt = (int*)carve(100000 * 4);
  int* bsums = (int*)carve(1024 * 4);
  int* rp[3];
  rp[0] = (int*)carve((NP + 1) * 4);
  rp[1] = (int*)carve((NS + 1) * 4);
  rp[2] = (int*)carve((NU + 1) * 4);
  int* srcs[3];
  srcs[0] = (int*)carve(400000 * 4);
  srcs[1] = (int*)carve(300000 * 4);
  srcs[2] = (int*)carve(300000 * 4);
  (void)ws_size;

  // ---- initial features ----
  for (int t = 0; t < 3; ++t) {
    k_init<<<TYPE_N[t], 128, 0, stream>>>(x_in[t], lin_w + t * 20 * 128, lin_b + t * 128,
                                          emb[t], nid[t], XsA + (size_t)TYPE_OFF[t] * 128,
                                          TYPE_N[t]);
  }

  // ---- CSR per edge type (by destination), srcs in slot order ----
  for (int et = 0; et < 3; ++et) {
    int E = ET_E[et];
    int Nd = TYPE_N[ET_DST[et]];
    const int* dstp = ei[et] + E;
    int nb = (Nd + 1023) / 1024;
    hipMemsetAsync(cnt, 0, (size_t)Nd * 4, stream);
    k_count<<<(E + 255) / 256, 256, 0, stream>>>(dstp, E, cnt);
    k_blocksum<<<nb, 256, 0, stream>>>(cnt, Nd, bsums);
    k_scan_bsums<<<1, 256, 0, stream>>>(bsums, nb);
    k_scan_apply<<<nb, 256, 0, stream>>>(cnt, bsums, rp[et], Nd);
    hipMemsetAsync(cnt, 0, (size_t)Nd * 4, stream);
    k_fill<<<(E + 255) / 256, 256, 0, stream>>>(ei[et], E, rp[et], cnt, srcs[et]);
  }

  const float scale = 0.08838834764831845f;  // 1/sqrt(128)

  for (int l = 0; l < 2; ++l) {
    const ushort* Xin = (l == 0) ? XsA : XsB;

    // ---- per-type weight prep ----
    for (int t = 0; t < 3; ++t) {
      int et = ET_OF_DSTTYPE[t];
      const float* Wk = qkv_w + (size_t)((l * 3 + t) * 3 + 1) * 16384;
      const float* bk = qkv_b + (size_t)((l * 3 + t) * 3 + 1) * 128;
      const float* We = W_edge + (size_t)(l * 3 + et) * 16384;
      k_keff<<<128, 128, 0, stream>>>(Wk, bk, We, Keff3 + t * 16384, bkeff3 + t * 128);
    }
    {
      dim3 g(64, 3);
      k_splitw<<<g, 256, 0, stream>>>(qkv_w + (size_t)(9 * l) * 16384, 3 * 16384,
                                      WtHi, WtLo, 3 * 16384);  // Q -> slot t*3+0
      k_splitw<<<g, 256, 0, stream>>>(Keff3, 16384, WtHi + 16384, WtLo + 16384,
                                      3 * 16384);              // Keff -> slot t*3+1
      k_splitw<<<g, 256, 0, stream>>>(qkv_w + (size_t)(9 * l + 2) * 16384, 3 * 16384,
                                      WtHi + 2 * 16384, WtLo + 2 * 16384,
                                      3 * 16384);              // V -> slot t*3+2
    }

    // ---- per-type fused Q/K/V GEMM ----
    for (int t = 0; t < 3; ++t) {
      int N = TYPE_N[t];
      size_t off = (size_t)TYPE_OFF[t] * 128;
      const float* bq = qkv_b + (size_t)((l * 3 + t) * 3 + 0) * 128;
      const float* bv = qkv_b + (size_t)((l * 3 + t) * 3 + 2) * 128;
      k_gemm3<<<(N + 127) / 128, 256, 0, stream>>>(
          Xin + off, WtHi + (size_t)t * 3 * 16384, WtLo + (size_t)t * 3 * 16384,
          bq, bkeff3 + t * 128, bv, Qb + off, Kb + off, Vb + off, N);
    }

    // ---- per-edge-type scores + aggregate ----
    for (int et = 0; et < 3; ++et) {
      int st = ET_SRC[et], dt = ET_DST[et];
      int Nd = TYPE_N[dt];
      size_t offs = (size_t)TYPE_OFF[st] * 128;
      size_t offd = (size_t)TYPE_OFF[dt] * 128;
      int grid = (Nd + 3) / 4;
      k_scores_csr<<<grid, 256, 0, stream>>>(rp[et], srcs[et], Qb + offs, Kb + offd,
                                             exb, den, scale, Nd);
      if (l == 0)
        k_agg_csr<0><<<grid, 256, 0, stream>>>(rp[et], srcs[et], exb, den, Vb + offs,
                                               XsB + offd, (float*)nullptr, Nd);
      else
        k_agg_csr<1><<<grid, 256, 0, stream>>>(rp[et], srcs[et], exb, den, Vb + offs,
                                               (ushort*)nullptr, out + offd, Nd);
    }
  }
}

// Round 6
// 638.748 us; speedup vs baseline: 2.9213x; 1.5526x over previous
//
#include <hip/hip_runtime.h>

#define NP 50000
#define NU 100000
#define NS 20000

typedef __attribute__((ext_vector_type(8))) short short8;
typedef __attribute__((ext_vector_type(4))) float f32x4;
typedef unsigned int uint32;

__device__ inline ushort f2bf(float f) {
  uint32 u = __float_as_uint(f);
  uint32 r = (u + 0x7FFF + ((u >> 16) & 1)) >> 16;
  return (ushort)r;
}
__device__ inline float bf2f(ushort h) { return __uint_as_float(((uint32)h) << 16); }

// ---------------------------------------------------------------------------
// init: s = x @ lin_w + lin_b + emb[node_id]; write bf16
// ---------------------------------------------------------------------------
__global__ __launch_bounds__(128) void k_init(const float* __restrict__ x,
                                              const float* __restrict__ lw,
                                              const float* __restrict__ lb,
                                              const float* __restrict__ emb,
                                              const int* __restrict__ nid,
                                              ushort* __restrict__ xb, int N) {
  int n = blockIdx.x;
  int d = threadIdx.x;
  if (n >= N) return;
  float s = lb[d];
#pragma unroll
  for (int j = 0; j < 20; ++j) s += x[n * 20 + j] * lw[j * 128 + d];
  s += emb[nid[n] * 128 + d];
  xb[n * 128 + d] = f2bf(s);
}

// ---------------------------------------------------------------------------
// batched Keff: y = l*3+t.  Keff[y][c][d] = sum_f Wk[c][f] * We[d][f]
// ---------------------------------------------------------------------------
__global__ __launch_bounds__(128) void k_keff(const float* __restrict__ qkv_w,
                                              const float* __restrict__ qkv_b,
                                              const float* __restrict__ W_edge,
                                              float* __restrict__ Keff,
                                              float* __restrict__ bkeff) {
  int y = blockIdx.y;  // l*3 + t
  int l = y / 3, t = y - l * 3;
  int et = (t == 0) ? 0 : (t == 1) ? 2 : 1;  // edge type with dst == t
  const float* Wk = qkv_w + (size_t)(y * 3 + 1) * 16384;
  const float* bk = qkv_b + (size_t)(y * 3 + 1) * 128;
  const float* We = W_edge + (size_t)(l * 3 + et) * 16384;
  float* Ko = Keff + (size_t)y * 16384;
  float* bo = bkeff + (size_t)y * 128;

  __shared__ float Wes[128][65];
  int c = blockIdx.x, tid = threadIdx.x;
  float s = 0.f, tb = 0.f;
  for (int f0 = 0; f0 < 128; f0 += 64) {
    __syncthreads();
    int fr = tid & 63, r0 = tid >> 6;
    for (int it = 0; it < 64; ++it) {
      int row = it * 2 + r0;
      Wes[row][fr] = We[row * 128 + f0 + fr];
    }
    __syncthreads();
#pragma unroll 16
    for (int fp = 0; fp < 64; ++fp) s += Wk[c * 128 + f0 + fp] * Wes[tid][fp];
    if (c == 0) {
      for (int fp = 0; fp < 64; ++fp) tb += bk[f0 + fp] * Wes[tid][fp];
    }
  }
  Ko[c * 128 + tid] = s;
  if (c == 0) bo[tid] = tb;
}

// ---------------------------------------------------------------------------
// split + transpose 128x128 f32 weight(s) -> Wt[n][k] hi/lo bf16 (batched y)
// ---------------------------------------------------------------------------
__global__ __launch_bounds__(256) void k_splitw(const float* __restrict__ W, int srcStride,
                                                ushort* __restrict__ hi,
                                                ushort* __restrict__ lo, int dstStride) {
  const float* src = W + (size_t)blockIdx.y * srcStride;
  ushort* h = hi + (size_t)blockIdx.y * dstStride;
  ushort* l = lo + (size_t)blockIdx.y * dstStride;
  int idx = blockIdx.x * 256 + threadIdx.x;  // 0..16383
  int n = idx >> 7, c = idx & 127;
  float f = src[c * 128 + n];
  ushort hb = f2bf(f);
  h[idx] = hb;
  l[idx] = f2bf(f - bf2f(hb));
}

// ---------------------------------------------------------------------------
// Triple-B MFMA GEMM v3: LDS-staged A (swizzled) AND LDS-staged epilogue so
// global stores are full-line 16B/lane coalesced (kills write amplification).
// ---------------------------------------------------------------------------
__global__ __launch_bounds__(256, 3) void k_gemm3(
    const ushort* __restrict__ A,
    const ushort* __restrict__ Whi, const ushort* __restrict__ Wlo,
    const float* __restrict__ bq, const float* __restrict__ bk,
    const float* __restrict__ bv,
    ushort* __restrict__ Yq, ushort* __restrict__ Yk, ushort* __restrict__ Yv,
    int M) {
  __shared__ ushort As[128 * 128];  // 32 KB
  __shared__ ushort Ys[64 * 128];   // 16 KB output staging
  int tid = threadIdx.x;
  int wave = tid >> 6, lane = tid & 63;
  int row0 = blockIdx.x * 128;
  int colw = wave * 32;
  int lrow = lane & 15, kgrp = lane >> 4;

  // ---- stage A tile: linear global read, swizzled LDS write ----
#pragma unroll
  for (int i = 0; i < 8; ++i) {
    int chunkLin = i * 256 + tid;
    int row = chunkLin >> 4;
    int chunk = chunkLin & 15;
    int grow = row0 + row;
    if (grow >= M) grow = M - 1;
    short8 v = *(const short8*)(A + (size_t)grow * 128 + chunk * 8);
    *(short8*)(As + row * 128 + (chunk ^ (row & 7)) * 8) = v;
  }
  __syncthreads();

  int x7 = lrow & 7;

  for (int bw = 0; bw < 3; ++bw) {
    f32x4 acc[8][2] = {};
#pragma unroll
    for (int s = 0; s < 4; ++s) {
      short8 bh[2], bl[2];
#pragma unroll
      for (int nt = 0; nt < 2; ++nt) {
        int col = colw + nt * 16 + lrow;
        size_t boff = (size_t)bw * 16384 + col * 128 + s * 32 + kgrp * 8;
        bh[nt] = *(const short8*)(Whi + boff);
        bl[nt] = *(const short8*)(Wlo + boff);
      }
      int c2 = (s * 4 + kgrp) ^ x7;
#pragma unroll
      for (int mt = 0; mt < 8; ++mt) {
        int row = mt * 16 + lrow;
        short8 a = *(const short8*)(As + row * 128 + c2 * 8);
        acc[mt][0] = __builtin_amdgcn_mfma_f32_16x16x32_bf16(a, bh[0], acc[mt][0], 0, 0, 0);
        acc[mt][0] = __builtin_amdgcn_mfma_f32_16x16x32_bf16(a, bl[0], acc[mt][0], 0, 0, 0);
        acc[mt][1] = __builtin_amdgcn_mfma_f32_16x16x32_bf16(a, bh[1], acc[mt][1], 0, 0, 0);
        acc[mt][1] = __builtin_amdgcn_mfma_f32_16x16x32_bf16(a, bl[1], acc[mt][1], 0, 0, 0);
      }
    }
    // ---- epilogue: stage 64-row half-tiles through LDS, stream out ----
    const float* bias = (bw == 0) ? bq : (bw == 1) ? bk : bv;
    ushort* Y = (bw == 0) ? Yq : (bw == 1) ? Yk : Yv;
    float b0 = bias[colw + lrow];
    float b1 = bias[colw + 16 + lrow];
    int col0i = colw + lrow;
    int col1i = colw + 16 + lrow;
#pragma unroll
    for (int half = 0; half < 2; ++half) {
      __syncthreads();  // Ys free (previous copy complete)
#pragma unroll
      for (int mt4 = 0; mt4 < 4; ++mt4) {
        int mt = half * 4 + mt4;
#pragma unroll
        for (int r = 0; r < 4; ++r) {
          int lr = mt4 * 16 + kgrp * 4 + r;
          int sw = lr & 7;
          Ys[lr * 128 + (((col0i >> 3) ^ sw) * 8) + (col0i & 7)] = f2bf(acc[mt][0][r] + b0);
          Ys[lr * 128 + (((col1i >> 3) ^ sw) * 8) + (col1i & 7)] = f2bf(acc[mt][1][r] + b1);
        }
      }
      __syncthreads();
#pragma unroll
      for (int i = 0; i < 4; ++i) {
        int chunk = i * 256 + tid;  // 0..1023
        int row = chunk >> 4, c = chunk & 15;
        int grow = row0 + half * 64 + row;
        if (grow < M)
          *(short8*)(Y + (size_t)grow * 128 + c * 8) =
              *(const short8*)(Ys + row * 128 + ((c ^ (row & 7)) * 8));
      }
    }
  }
}

// ---------------------------------------------------------------------------
// FUSED edge kernel: out[dst] = (sum_e ex_e * V[src_e]) / (sum_e ex_e)
// one wave per dst; 4 edge-slots x 16 lanes; Q and V rows gathered together.
// MODE 0 -> relu + write bf16; MODE 1 -> write f32 (final output)
// ---------------------------------------------------------------------------
template <int MODE>
__global__ __launch_bounds__(256) void k_edge(
    const int* __restrict__ rowptr, const int* __restrict__ srcs,
    const ushort* __restrict__ Q, const ushort* __restrict__ K,
    const ushort* __restrict__ V,
    ushort* __restrict__ obf, float* __restrict__ of, float scale, int Nd) {
  int wid = (blockIdx.x * 256 + threadIdx.x) >> 6;
  if (wid >= Nd) return;
  int lane = threadIdx.x & 63;
  int sub = lane & 15, eslot = lane >> 4;
  int s0 = rowptr[wid], s1 = rowptr[wid + 1];

  float kf[8];
  {
    short8 kv = *(const short8*)(K + (size_t)wid * 128 + sub * 8);
#pragma unroll
    for (int j = 0; j < 8; ++j) kf[j] = bf2f((ushort)kv[j]);
  }

  float acc[8] = {};
  float dsum = 0.f;
  int k = s0 + eslot;
  for (; k + 4 < s1; k += 8) {
    int src0 = srcs[k];
    int src1 = srcs[k + 4];
    short8 q0 = *(const short8*)(Q + (size_t)src0 * 128 + sub * 8);
    short8 v0 = *(const short8*)(V + (size_t)src0 * 128 + sub * 8);
    short8 q1 = *(const short8*)(Q + (size_t)src1 * 128 + sub * 8);
    short8 v1 = *(const short8*)(V + (size_t)src1 * 128 + sub * 8);
    float p0 = 0.f, p1 = 0.f;
#pragma unroll
    for (int j = 0; j < 8; ++j) {
      p0 += bf2f((ushort)q0[j]) * kf[j];
      p1 += bf2f((ushort)q1[j]) * kf[j];
    }
    p0 += __shfl_xor(p0, 8, 16); p0 += __shfl_xor(p0, 4, 16);
    p0 += __shfl_xor(p0, 2, 16); p0 += __shfl_xor(p0, 1, 16);
    p1 += __shfl_xor(p1, 8, 16); p1 += __shfl_xor(p1, 4, 16);
    p1 += __shfl_xor(p1, 2, 16); p1 += __shfl_xor(p1, 1, 16);
    float sa = p0 * scale; sa = (sa > 0.f) ? sa : 0.01f * sa;
    float sb = p1 * scale; sb = (sb > 0.f) ? sb : 0.01f * sb;
    float e0 = __expf(sa), e1 = __expf(sb);
    dsum += e0 + e1;
#pragma unroll
    for (int j = 0; j < 8; ++j)
      acc[j] += e0 * bf2f((ushort)v0[j]) + e1 * bf2f((ushort)v1[j]);
  }
  if (k < s1) {
    int src0 = srcs[k];
    short8 q0 = *(const short8*)(Q + (size_t)src0 * 128 + sub * 8);
    short8 v0 = *(const short8*)(V + (size_t)src0 * 128 + sub * 8);
    float p0 = 0.f;
#pragma unroll
    for (int j = 0; j < 8; ++j) p0 += bf2f((ushort)q0[j]) * kf[j];
    p0 += __shfl_xor(p0, 8, 16); p0 += __shfl_xor(p0, 4, 16);
    p0 += __shfl_xor(p0, 2, 16); p0 += __shfl_xor(p0, 1, 16);
    float sa = p0 * scale; sa = (sa > 0.f) ? sa : 0.01f * sa;
    float e0 = __expf(sa);
    dsum += e0;
#pragma unroll
    for (int j = 0; j < 8; ++j) acc[j] += e0 * bf2f((ushort)v0[j]);
  }

  // cross-eslot reduction (every lane ends with the full sums)
#pragma unroll
  for (int j = 0; j < 8; ++j) {
    acc[j] += __shfl_xor(acc[j], 16, 64);
    acc[j] += __shfl_xor(acc[j], 32, 64);
  }
  dsum += __shfl_xor(dsum, 16, 64);
  dsum += __shfl_xor(dsum, 32, 64);
  float inv = (s1 > s0) ? 1.f / dsum : 0.f;

  if (MODE == 0) {
    if (eslot == 0) {
      short8 ov;
#pragma unroll
      for (int j = 0; j < 8; ++j) {
        float f = fmaxf(acc[j] * inv, 0.f);
        ov[j] = (short)f2bf(f);
      }
      *(short8*)(obf + (size_t)wid * 128 + sub * 8) = ov;
    }
  } else {
    if (eslot < 2) {
      float4 w;
      int b = eslot * 4;
      w.x = acc[b + 0] * inv; w.y = acc[b + 1] * inv;
      w.z = acc[b + 2] * inv; w.w = acc[b + 3] * inv;
      *(float4*)(of + (size_t)wid * 128 + sub * 8 + eslot * 4) = w;
    }
  }
}

// ---------------------------------------------------------------------------
// CSR build: count -> hierarchical scan -> fill
// ---------------------------------------------------------------------------
__global__ void k_count(const int* __restrict__ dst, int E, int* __restrict__ counts) {
  int e = blockIdx.x * 256 + threadIdx.x;
  if (e < E) atomicAdd(&counts[dst[e]], 1);
}

__global__ __launch_bounds__(256) void k_blocksum(const int* __restrict__ c, int N,
                                                  int* __restrict__ bs) {
  int base = blockIdx.x * 1024;
  int t = threadIdx.x;
  int s = 0;
#pragma unroll
  for (int j = 0; j < 4; ++j) {
    int i = base + t * 4 + j;
    if (i < N) s += c[i];
  }
#pragma unroll
  for (int off = 32; off; off >>= 1) s += __shfl_down(s, off, 64);
  __shared__ int wsm[4];
  if ((t & 63) == 0) wsm[t >> 6] = s;
  __syncthreads();
  if (t == 0) bs[blockIdx.x] = wsm[0] + wsm[1] + wsm[2] + wsm[3];
}

__global__ __launch_bounds__(256) void k_scan_bsums(int* __restrict__ bs, int nb) {
  __shared__ int sm[256];
  int t = threadIdx.x;
  int v[4];
  int s = 0;
#pragma unroll
  for (int j = 0; j < 4; ++j) {
    int i = t * 4 + j;
    v[j] = (i < nb) ? bs[i] : 0;
    s += v[j];
  }
  sm[t] = s;
  __syncthreads();
  for (int off = 1; off < 256; off <<= 1) {
    int x = (t >= off) ? sm[t - off] : 0;
    __syncthreads();
    sm[t] += x;
    __syncthreads();
  }
  int run = t ? sm[t - 1] : 0;
#pragma unroll
  for (int j = 0; j < 4; ++j) {
    int i = t * 4 + j;
    if (i < nb) {
      int tmp = v[j];
      bs[i] = run;
      run += tmp;
    }
  }
}

__global__ __launch_bounds__(256) void k_scan_apply(const int* __restrict__ c,
                                                    const int* __restrict__ bofs,
                                                    int* __restrict__ rowptr, int N) {
  __shared__ int sm[256];
  int base = blockIdx.x * 1024, t = threadIdx.x;
  int v[4];
  int s = 0;
#pragma unroll
  for (int j = 0; j < 4; ++j) {
    int i = base + t * 4 + j;
    v[j] = (i < N) ? c[i] : 0;
    s += v[j];
  }
  sm[t] = s;
  __syncthreads();
  for (int off = 1; off < 256; off <<= 1) {
    int x = (t >= off) ? sm[t - off] : 0;
    __syncthreads();
    sm[t] += x;
    __syncthreads();
  }
  int run = bofs[blockIdx.x] + (t ? sm[t - 1] : 0);
#pragma unroll
  for (int j = 0; j < 4; ++j) {
    int i = base + t * 4 + j;
    if (i < N) {
      run += v[j];
      rowptr[i + 1] = run;
    }
  }
  if (blockIdx.x == 0 && t == 0) rowptr[0] = 0;
}

__global__ void k_fill(const int* __restrict__ ei, int E,
                       const int* __restrict__ rowptr, int* __restrict__ cursor,
                       int* __restrict__ srcs) {
  int e = blockIdx.x * 256 + threadIdx.x;
  if (e < E) {
    int s = ei[e];
    int d = ei[E + e];
    int p = atomicAdd(&cursor[d], 1);
    srcs[rowptr[d] + p] = s;
  }
}

// ---------------------------------------------------------------------------

extern "C" void kernel_launch(void* const* d_in, const int* in_sizes, int n_in,
                              void* d_out, int out_size, void* d_ws, size_t ws_size,
                              hipStream_t stream) {
  const float* x_in[3] = {(const float*)d_in[0], (const float*)d_in[1], (const float*)d_in[2]};
  const int* nid[3] = {(const int*)d_in[3], (const int*)d_in[4], (const int*)d_in[5]};
  const int* ei[3] = {(const int*)d_in[6], (const int*)d_in[7], (const int*)d_in[8]};
  const float* lin_w = (const float*)d_in[9];
  const float* lin_b = (const float*)d_in[10];
  const float* emb[3] = {(const float*)d_in[11], (const float*)d_in[12], (const float*)d_in[13]};
  const float* qkv_w = (const float*)d_in[14];
  const float* qkv_b = (const float*)d_in[15];
  const float* W_edge = (const float*)d_in[16];
  float* out = (float*)d_out;

  const int TYPE_N[3] = {NP, NU, NS};
  const int TYPE_OFF[3] = {0, NP, NP + NU};
  const int ET_SRC[3] = {1, 0, 2};
  const int ET_DST[3] = {0, 2, 1};
  const int ET_E[3] = {400000, 300000, 300000};

  char* ws = (char*)d_ws;
  size_t o = 0;
  auto carve = [&](size_t bytes) {
    char* p = ws + o;
    o = (o + bytes + 255) & ~(size_t)255;
    return p;
  };
  ushort* XsA = (ushort*)carve((size_t)170000 * 128 * 2);
  ushort* XsB = (ushort*)carve((size_t)170000 * 128 * 2);
  ushort* Qb = (ushort*)carve((size_t)170000 * 128 * 2);
  ushort* Kb = (ushort*)carve((size_t)170000 * 128 * 2);
  ushort* Vb = (ushort*)carve((size_t)170000 * 128 * 2);
  float* Keff6 = (float*)carve((size_t)6 * 16384 * 4);
  float* bkeff6 = (float*)carve(6 * 128 * 4);
  ushort* WtHi = (ushort*)carve((size_t)18 * 16384 * 2);  // [l*3+t][{Q,K,V}]
  ushort* WtLo = (ushort*)carve((size_t)18 * 16384 * 2);
  int* cnt = (int*)carve(100000 * 4);
  int* bsums = (int*)carve(1024 * 4);
  int* rp[3];
  rp[0] = (int*)carve((NP + 1) * 4);
  rp[1] = (int*)carve((NS + 1) * 4);
  rp[2] = (int*)carve((NU + 1) * 4);
  int* srcs[3];
  srcs[0] = (int*)carve(400000 * 4);
  srcs[1] = (int*)carve(300000 * 4);
  srcs[2] = (int*)carve(300000 * 4);
  (void)ws_size;

  // ---- initial features ----
  for (int t = 0; t < 3; ++t) {
    k_init<<<TYPE_N[t], 128, 0, stream>>>(x_in[t], lin_w + t * 20 * 128, lin_b + t * 128,
                                          emb[t], nid[t], XsA + (size_t)TYPE_OFF[t] * 128,
                                          TYPE_N[t]);
  }

  // ---- CSR per edge type (by destination), srcs in slot order ----
  for (int et = 0; et < 3; ++et) {
    int E = ET_E[et];
    int Nd = TYPE_N[ET_DST[et]];
    const int* dstp = ei[et] + E;
    int nb = (Nd + 1023) / 1024;
    hipMemsetAsync(cnt, 0, (size_t)Nd * 4, stream);
    k_count<<<(E + 255) / 256, 256, 0, stream>>>(dstp, E, cnt);
    k_blocksum<<<nb, 256, 0, stream>>>(cnt, Nd, bsums);
    k_scan_bsums<<<1, 256, 0, stream>>>(bsums, nb);
    k_scan_apply<<<nb, 256, 0, stream>>>(cnt, bsums, rp[et], Nd);
    hipMemsetAsync(cnt, 0, (size_t)Nd * 4, stream);
    k_fill<<<(E + 255) / 256, 256, 0, stream>>>(ei[et], E, rp[et], cnt, srcs[et]);
  }

  // ---- weight prep for BOTH layers, batched ----
  {
    dim3 gk(128, 6);
    k_keff<<<gk, 128, 0, stream>>>(qkv_w, qkv_b, W_edge, Keff6, bkeff6);
    dim3 gs(64, 6);
    k_splitw<<<gs, 256, 0, stream>>>(qkv_w, 3 * 16384, WtHi, WtLo, 3 * 16384);
    k_splitw<<<gs, 256, 0, stream>>>(Keff6, 16384, WtHi + 16384, WtLo + 16384, 3 * 16384);
    k_splitw<<<gs, 256, 0, stream>>>(qkv_w + 2 * 16384, 3 * 16384, WtHi + 2 * 16384,
                                     WtLo + 2 * 16384, 3 * 16384);
  }

  const float scale = 0.08838834764831845f;  // 1/sqrt(128)

  for (int l = 0; l < 2; ++l) {
    const ushort* Xin = (l == 0) ? XsA : XsB;

    // ---- per-type fused Q/K/V GEMM ----
    for (int t = 0; t < 3; ++t) {
      int N = TYPE_N[t];
      int y = l * 3 + t;
      size_t off = (size_t)TYPE_OFF[t] * 128;
      const float* bq = qkv_b + (size_t)(y * 3 + 0) * 128;
      const float* bv = qkv_b + (size_t)(y * 3 + 2) * 128;
      k_gemm3<<<(N + 127) / 128, 256, 0, stream>>>(
          Xin + off, WtHi + (size_t)y * 3 * 16384, WtLo + (size_t)y * 3 * 16384,
          bq, bkeff6 + y * 128, bv, Qb + off, Kb + off, Vb + off, N);
    }

    // ---- fused per-edge-type scores+aggregate ----
    for (int et = 0; et < 3; ++et) {
      int st = ET_SRC[et], dt = ET_DST[et];
      int Nd = TYPE_N[dt];
      size_t offs = (size_t)TYPE_OFF[st] * 128;
      size_t offd = (size_t)TYPE_OFF[dt] * 128;
      int grid = (Nd + 3) / 4;
      if (l == 0)
        k_edge<0><<<grid, 256, 0, stream>>>(rp[et], srcs[et], Qb + offs, Kb + offd,
                                            Vb + offs, XsB + offd, (float*)nullptr,
                                            scale, Nd);
      else
        k_edge<1><<<grid, 256, 0, stream>>>(rp[et], srcs[et], Qb + offs, Kb + offd,
                                            Vb + offs, (ushort*)nullptr, out + offd,
                                            scale, Nd);
    }
  }
}

// Round 7
// 580.305 us; speedup vs baseline: 3.2155x; 1.1007x over previous
//
#include <hip/hip_runtime.h>

#define NP 50000
#define NU 100000
#define NS 20000
#define NTOT 170000
#define E0 400000
#define E1 300000
#define E2 300000

typedef __attribute__((ext_vector_type(8))) short short8;
typedef __attribute__((ext_vector_type(4))) float f32x4;
typedef unsigned int uint32;

__device__ inline ushort f2bf(float f) {
  uint32 u = __float_as_uint(f);
  uint32 r = (u + 0x7FFF + ((u >> 16) & 1)) >> 16;
  return (ushort)r;
}
__device__ inline float bf2f(ushort h) { return __uint_as_float(((uint32)h) << 16); }

// ---------------------------------------------------------------------------
// fused init for ALL nodes: 32 threads/node, 4 dims/thread.
// type boundaries (50000, 150000) are 8-node (block) aligned.
// ---------------------------------------------------------------------------
__global__ __launch_bounds__(256) void k_init_all(
    const float* __restrict__ xp, const float* __restrict__ xu,
    const float* __restrict__ xs, const int* __restrict__ nidp,
    const int* __restrict__ nidu, const int* __restrict__ nids,
    const float* __restrict__ lin_w, const float* __restrict__ lin_b,
    const float* __restrict__ embp, const float* __restrict__ embu,
    const float* __restrict__ embs, ushort* __restrict__ xb) {
  int tid = threadIdx.x;
  int node = blockIdx.x * 8 + (tid >> 5);
  int dg = tid & 31;
  int t, local;
  const float* x;
  const int* nid;
  const float* emb;
  if (node < NP) { t = 0; local = node; x = xp; nid = nidp; emb = embp; }
  else if (node < NP + NU) { t = 1; local = node - NP; x = xu; nid = nidu; emb = embu; }
  else { t = 2; local = node - NP - NU; x = xs; nid = nids; emb = embs; }
  const float* lw = lin_w + t * 20 * 128;
  int d = dg * 4;
  float xv = (dg < 20) ? x[local * 20 + dg] : 0.f;
  float4 s = *(const float4*)&emb[(size_t)nid[local] * 128 + d];
  float4 b = *(const float4*)&lin_b[t * 128 + d];
  s.x += b.x; s.y += b.y; s.z += b.z; s.w += b.w;
#pragma unroll
  for (int j = 0; j < 20; ++j) {
    float xj = __shfl(xv, j, 32);
    float4 w = *(const float4*)&lw[j * 128 + d];
    s.x += xj * w.x; s.y += xj * w.y; s.z += xj * w.z; s.w += xj * w.w;
  }
  ushort4 o;
  o.x = f2bf(s.x); o.y = f2bf(s.y); o.z = f2bf(s.z); o.w = f2bf(s.w);
  *(ushort4*)&xb[(size_t)node * 128 + d] = o;
}

// ---------------------------------------------------------------------------
// batched Keff: y = l*3+t.  Keff[y][c][d] = sum_f Wk[c][f] * We[d][f]
// ---------------------------------------------------------------------------
__global__ __launch_bounds__(128) void k_keff(const float* __restrict__ qkv_w,
                                              const float* __restrict__ qkv_b,
                                              const float* __restrict__ W_edge,
                                              float* __restrict__ Keff,
                                              float* __restrict__ bkeff) {
  int y = blockIdx.y;  // l*3 + t
  int l = y / 3, t = y - l * 3;
  int et = (t == 0) ? 0 : (t == 1) ? 2 : 1;  // edge type with dst == t
  const float* Wk = qkv_w + (size_t)(y * 3 + 1) * 16384;
  const float* bk = qkv_b + (size_t)(y * 3 + 1) * 128;
  const float* We = W_edge + (size_t)(l * 3 + et) * 16384;
  float* Ko = Keff + (size_t)y * 16384;
  float* bo = bkeff + (size_t)y * 128;

  __shared__ float Wes[128][65];
  int c = blockIdx.x, tid = threadIdx.x;
  float s = 0.f, tb = 0.f;
  for (int f0 = 0; f0 < 128; f0 += 64) {
    __syncthreads();
    int fr = tid & 63, r0 = tid >> 6;
    for (int it = 0; it < 64; ++it) {
      int row = it * 2 + r0;
      Wes[row][fr] = We[row * 128 + f0 + fr];
    }
    __syncthreads();
#pragma unroll 16
    for (int fp = 0; fp < 64; ++fp) s += Wk[c * 128 + f0 + fp] * Wes[tid][fp];
    if (c == 0) {
      for (int fp = 0; fp < 64; ++fp) tb += bk[f0 + fp] * Wes[tid][fp];
    }
  }
  Ko[c * 128 + tid] = s;
  if (c == 0) bo[tid] = tb;
}

// ---------------------------------------------------------------------------
// split+transpose all 18 weights in one launch.
// slot s: y=s/3, r=s%3: r0 = Wq[y], r1 = Keff[y], r2 = Wv[y]
// ---------------------------------------------------------------------------
__global__ __launch_bounds__(256) void k_splitw18(const float* __restrict__ qkv_w,
                                                  const float* __restrict__ Keff6,
                                                  ushort* __restrict__ hi,
                                                  ushort* __restrict__ lo) {
  int slot = blockIdx.y;
  int y = slot / 3, r = slot - y * 3;
  const float* src = (r == 1) ? (Keff6 + (size_t)y * 16384)
                              : (qkv_w + (size_t)(y * 3 + ((r == 0) ? 0 : 2)) * 16384);
  ushort* h = hi + (size_t)slot * 16384;
  ushort* l = lo + (size_t)slot * 16384;
  int idx = blockIdx.x * 256 + threadIdx.x;  // 0..16383
  int n = idx >> 7, c = idx & 127;
  float f = src[c * 128 + n];
  ushort hb = f2bf(f);
  h[idx] = hb;
  l[idx] = f2bf(f - bf2f(hb));
}

// ---------------------------------------------------------------------------
// Triple-B MFMA GEMM, all 3 types in one launch (block -> type by range).
// LDS-staged A (swizzled) + LDS-staged epilogue (full-line stores).
// ---------------------------------------------------------------------------
#define GB0 391   // ceil(NP/128)
#define GB1 782   // ceil(NU/128)
#define GB2 157   // ceil(NS/128)
__global__ __launch_bounds__(256, 3) void k_gemm3(
    const ushort* __restrict__ Xin,
    const ushort* __restrict__ WtHi, const ushort* __restrict__ WtLo,
    const float* __restrict__ qkv_b, const float* __restrict__ bkeff6,
    ushort* __restrict__ Qb, ushort* __restrict__ Kb, ushort* __restrict__ Vb,
    int l) {
  __shared__ ushort As[128 * 128];  // 32 KB
  __shared__ ushort Ys[64 * 128];   // 16 KB output staging
  int bid = blockIdx.x;
  int t, row0, M, moff;
  if (bid < GB0) { t = 0; row0 = bid * 128; M = NP; moff = 0; }
  else if (bid < GB0 + GB1) { t = 1; row0 = (bid - GB0) * 128; M = NU; moff = NP; }
  else { t = 2; row0 = (bid - GB0 - GB1) * 128; M = NS; moff = NP + NU; }
  int y = l * 3 + t;
  const ushort* A = Xin + (size_t)moff * 128;
  const ushort* Whi = WtHi + (size_t)y * 3 * 16384;
  const ushort* Wlo = WtLo + (size_t)y * 3 * 16384;
  const float* bq = qkv_b + (size_t)(y * 3 + 0) * 128;
  const float* bk = bkeff6 + (size_t)y * 128;
  const float* bv = qkv_b + (size_t)(y * 3 + 2) * 128;

  int tid = threadIdx.x;
  int wave = tid >> 6, lane = tid & 63;
  int colw = wave * 32;
  int lrow = lane & 15, kgrp = lane >> 4;

  // ---- stage A tile: linear global read, swizzled LDS write ----
#pragma unroll
  for (int i = 0; i < 8; ++i) {
    int chunkLin = i * 256 + tid;
    int row = chunkLin >> 4;
    int chunk = chunkLin & 15;
    int grow = row0 + row;
    if (grow >= M) grow = M - 1;
    short8 v = *(const short8*)(A + (size_t)grow * 128 + chunk * 8);
    *(short8*)(As + row * 128 + (chunk ^ (row & 7)) * 8) = v;
  }
  __syncthreads();

  int x7 = lrow & 7;

  for (int bw = 0; bw < 3; ++bw) {
    f32x4 acc[8][2] = {};
#pragma unroll
    for (int s = 0; s < 4; ++s) {
      short8 bh[2], bl[2];
#pragma unroll
      for (int nt = 0; nt < 2; ++nt) {
        int col = colw + nt * 16 + lrow;
        size_t boff = (size_t)bw * 16384 + col * 128 + s * 32 + kgrp * 8;
        bh[nt] = *(const short8*)(Whi + boff);
        bl[nt] = *(const short8*)(Wlo + boff);
      }
      int c2 = (s * 4 + kgrp) ^ x7;
#pragma unroll
      for (int mt = 0; mt < 8; ++mt) {
        int row = mt * 16 + lrow;
        short8 a = *(const short8*)(As + row * 128 + c2 * 8);
        acc[mt][0] = __builtin_amdgcn_mfma_f32_16x16x32_bf16(a, bh[0], acc[mt][0], 0, 0, 0);
        acc[mt][0] = __builtin_amdgcn_mfma_f32_16x16x32_bf16(a, bl[0], acc[mt][0], 0, 0, 0);
        acc[mt][1] = __builtin_amdgcn_mfma_f32_16x16x32_bf16(a, bh[1], acc[mt][1], 0, 0, 0);
        acc[mt][1] = __builtin_amdgcn_mfma_f32_16x16x32_bf16(a, bl[1], acc[mt][1], 0, 0, 0);
      }
    }
    const float* bias = (bw == 0) ? bq : (bw == 1) ? bk : bv;
    ushort* Y = ((bw == 0) ? Qb : (bw == 1) ? Kb : Vb) + (size_t)moff * 128;
    float b0 = bias[colw + lrow];
    float b1 = bias[colw + 16 + lrow];
    int col0i = colw + lrow;
    int col1i = colw + 16 + lrow;
#pragma unroll
    for (int half = 0; half < 2; ++half) {
      __syncthreads();
#pragma unroll
      for (int mt4 = 0; mt4 < 4; ++mt4) {
        int mt = half * 4 + mt4;
#pragma unroll
        for (int r = 0; r < 4; ++r) {
          int lr = mt4 * 16 + kgrp * 4 + r;
          int sw = lr & 7;
          Ys[lr * 128 + (((col0i >> 3) ^ sw) * 8) + (col0i & 7)] = f2bf(acc[mt][0][r] + b0);
          Ys[lr * 128 + (((col1i >> 3) ^ sw) * 8) + (col1i & 7)] = f2bf(acc[mt][1][r] + b1);
        }
      }
      __syncthreads();
#pragma unroll
      for (int i = 0; i < 4; ++i) {
        int chunk = i * 256 + tid;
        int row = chunk >> 4, c = chunk & 15;
        int grow = row0 + half * 64 + row;
        if (grow < M)
          *(short8*)(Y + (size_t)grow * 128 + c * 8) =
              *(const short8*)(Ys + row * 128 + ((c ^ (row & 7)) * 8));
      }
    }
  }
}

// ---------------------------------------------------------------------------
// FUSED edge kernel, ALL edge types in one launch (global CSR, 170k rows):
// rows [0,50k)=et0 (dst proxy, src user), [50k,70k)=et1 (dst server, src
// proxy), [70k,170k)=et2 (dst user, src server).
// one wave per row; 8 edge-slots x 8 lanes; 16 dims/lane.
// ---------------------------------------------------------------------------
template <int MODE>
__global__ __launch_bounds__(256) void k_edge(
    const int* __restrict__ rowptr, const int* __restrict__ srcs,
    const ushort* __restrict__ Q, const ushort* __restrict__ K,
    const ushort* __restrict__ V,
    ushort* __restrict__ obf, float* __restrict__ of, float scale) {
  int wid = (blockIdx.x * 256 + threadIdx.x) >> 6;
  if (wid >= NTOT) return;
  int lane = threadIdx.x & 63;
  int sub = lane & 7, eslot = lane >> 3;
  int dstNode, srcBase;
  if (wid < NP) { dstNode = wid; srcBase = NP; }
  else if (wid < NP + NS) { dstNode = wid + 100000; srcBase = 0; }
  else { dstNode = wid - NS; srcBase = NP + NU; }

  int s0 = rowptr[wid], s1 = rowptr[wid + 1];

  float kf[16];
  {
    const ushort* kr = K + (size_t)dstNode * 128 + sub * 16;
    short8 k0 = *(const short8*)kr;
    short8 k1 = *(const short8*)(kr + 8);
#pragma unroll
    for (int j = 0; j < 8; ++j) {
      kf[j] = bf2f((ushort)k0[j]);
      kf[8 + j] = bf2f((ushort)k1[j]);
    }
  }

  float acc[16] = {};
  float dsum = 0.f;
  for (int k = s0 + eslot; k < s1; k += 8) {
    int src = srcBase + srcs[k];
    const ushort* qr = Q + (size_t)src * 128 + sub * 16;
    const ushort* vr = V + (size_t)src * 128 + sub * 16;
    short8 q0 = *(const short8*)qr;
    short8 q1 = *(const short8*)(qr + 8);
    short8 v0 = *(const short8*)vr;
    short8 v1 = *(const short8*)(vr + 8);
    float p = 0.f;
#pragma unroll
    for (int j = 0; j < 8; ++j)
      p += bf2f((ushort)q0[j]) * kf[j] + bf2f((ushort)q1[j]) * kf[8 + j];
    p += __shfl_xor(p, 4, 8);
    p += __shfl_xor(p, 2, 8);
    p += __shfl_xor(p, 1, 8);
    float s = p * scale;
    s = (s > 0.f) ? s : 0.01f * s;
    float e = __expf(s);
    dsum += e;
#pragma unroll
    for (int j = 0; j < 8; ++j) {
      acc[j] += e * bf2f((ushort)v0[j]);
      acc[8 + j] += e * bf2f((ushort)v1[j]);
    }
  }

  // cross-eslot reduction (lanes with same sub)
#pragma unroll
  for (int j = 0; j < 16; ++j) {
    acc[j] += __shfl_xor(acc[j], 8, 64);
    acc[j] += __shfl_xor(acc[j], 16, 64);
    acc[j] += __shfl_xor(acc[j], 32, 64);
  }
  dsum += __shfl_xor(dsum, 8, 64);
  dsum += __shfl_xor(dsum, 16, 64);
  dsum += __shfl_xor(dsum, 32, 64);
  float inv = (s1 > s0) ? 1.f / dsum : 0.f;

  if (MODE == 0) {
    if (eslot == 0) {
      short8 o0, o1;
#pragma unroll
      for (int j = 0; j < 8; ++j) {
        o0[j] = (short)f2bf(fmaxf(acc[j] * inv, 0.f));
        o1[j] = (short)f2bf(fmaxf(acc[8 + j] * inv, 0.f));
      }
      ushort* orow = obf + (size_t)dstNode * 128 + sub * 16;
      *(short8*)orow = o0;
      *(short8*)(orow + 8) = o1;
    }
  } else {
    if (eslot < 4) {
      int b = eslot * 4;
      float4 w;
      w.x = acc[b + 0] * inv; w.y = acc[b + 1] * inv;
      w.z = acc[b + 2] * inv; w.w = acc[b + 3] * inv;
      *(float4*)(of + (size_t)dstNode * 128 + sub * 16 + b) = w;
    }
  }
}

// ---------------------------------------------------------------------------
// global CSR build over all 3 edge types
// edge e: [0,400k)=et0, [400k,700k)=et1, [700k,1M)=et2
// ---------------------------------------------------------------------------
__global__ void k_count_all(const int* __restrict__ e0, const int* __restrict__ e1,
                            const int* __restrict__ e2, int* __restrict__ cnt) {
  int e = blockIdx.x * 256 + threadIdx.x;
  if (e < E0) atomicAdd(&cnt[e0[E0 + e]], 1);
  else if (e < E0 + E1) atomicAdd(&cnt[NP + e1[E1 + (e - E0)]], 1);
  else if (e < E0 + E1 + E2) atomicAdd(&cnt[NP + NS + e2[E2 + (e - E0 - E1)]], 1);
}

__global__ void k_fill_all(const int* __restrict__ e0, const int* __restrict__ e1,
                           const int* __restrict__ e2, const int* __restrict__ rowptr,
                           int* __restrict__ cur, int* __restrict__ srcs) {
  int e = blockIdx.x * 256 + threadIdx.x;
  int row, src;
  if (e < E0) { row = e0[E0 + e]; src = e0[e]; }
  else if (e < E0 + E1) { row = NP + e1[E1 + (e - E0)]; src = e1[e - E0]; }
  else if (e < E0 + E1 + E2) { row = NP + NS + e2[E2 + (e - E0 - E1)]; src = e2[e - E0 - E1]; }
  else return;
  int p = atomicAdd(&cur[row], 1);
  srcs[rowptr[row] + p] = src;
}

__global__ __launch_bounds__(256) void k_blocksum(const int* __restrict__ c, int N,
                                                  int* __restrict__ bs) {
  int base = blockIdx.x * 1024;
  int t = threadIdx.x;
  int s = 0;
#pragma unroll
  for (int j = 0; j < 4; ++j) {
    int i = base + t * 4 + j;
    if (i < N) s += c[i];
  }
#pragma unroll
  for (int off = 32; off; off >>= 1) s += __shfl_down(s, off, 64);
  __shared__ int wsm[4];
  if ((t & 63) == 0) wsm[t >> 6] = s;
  __syncthreads();
  if (t == 0) bs[blockIdx.x] = wsm[0] + wsm[1] + wsm[2] + wsm[3];
}

__global__ __launch_bounds__(256) void k_scan_bsums(int* __restrict__ bs, int nb) {
  __shared__ int sm[256];
  int t = threadIdx.x;
  int v[4];
  int s = 0;
#pragma unroll
  for (int j = 0; j < 4; ++j) {
    int i = t * 4 + j;
    v[j] = (i < nb) ? bs[i] : 0;
    s += v[j];
  }
  sm[t] = s;
  __syncthreads();
  for (int off = 1; off < 256; off <<= 1) {
    int x = (t >= off) ? sm[t - off] : 0;
    __syncthreads();
    sm[t] += x;
    __syncthreads();
  }
  int run = t ? sm[t - 1] : 0;
#pragma unroll
  for (int j = 0; j < 4; ++j) {
    int i = t * 4 + j;
    if (i < nb) {
      int tmp = v[j];
      bs[i] = run;
      run += tmp;
    }
  }
}

__global__ __launch_bounds__(256) void k_scan_apply(const int* __restrict__ c,
                                                    const int* __restrict__ bofs,
                                                    int* __restrict__ rowptr, int N) {
  __shared__ int sm[256];
  int base = blockIdx.x * 1024, t = threadIdx.x;
  int v[4];
  int s = 0;
#pragma unroll
  for (int j = 0; j < 4; ++j) {
    int i = base + t * 4 + j;
    v[j] = (i < N) ? c[i] : 0;
    s += v[j];
  }
  sm[t] = s;
  __syncthreads();
  for (int off = 1; off < 256; off <<= 1) {
    int x = (t >= off) ? sm[t - off] : 0;
    __syncthreads();
    sm[t] += x;
    __syncthreads();
  }
  int run = bofs[blockIdx.x] + (t ? sm[t - 1] : 0);
#pragma unroll
  for (int j = 0; j < 4; ++j) {
    int i = base + t * 4 + j;
    if (i < N) {
      run += v[j];
      rowptr[i + 1] = run;
    }
  }
  if (blockIdx.x == 0 && t == 0) rowptr[0] = 0;
}

// ---------------------------------------------------------------------------

extern "C" void kernel_launch(void* const* d_in, const int* in_sizes, int n_in,
                              void* d_out, int out_size, void* d_ws, size_t ws_size,
                              hipStream_t stream) {
  const float* x_in[3] = {(const float*)d_in[0], (const float*)d_in[1], (const float*)d_in[2]};
  const int* nid[3] = {(const int*)d_in[3], (const int*)d_in[4], (const int*)d_in[5]};
  const int* ei[3] = {(const int*)d_in[6], (const int*)d_in[7], (const int*)d_in[8]};
  const float* lin_w = (const float*)d_in[9];
  const float* lin_b = (const float*)d_in[10];
  const float* emb[3] = {(const float*)d_in[11], (const float*)d_in[12], (const float*)d_in[13]};
  const float* qkv_w = (const float*)d_in[14];
  const float* qkv_b = (const float*)d_in[15];
  const float* W_edge = (const float*)d_in[16];
  float* out = (float*)d_out;

  char* ws = (char*)d_ws;
  size_t o = 0;
  auto carve = [&](size_t bytes) {
    char* p = ws + o;
    o = (o + bytes + 255) & ~(size_t)255;
    return p;
  };
  ushort* XsA = (ushort*)carve((size_t)NTOT * 128 * 2);
  ushort* XsB = (ushort*)carve((size_t)NTOT * 128 * 2);
  ushort* Qb = (ushort*)carve((size_t)NTOT * 128 * 2);
  ushort* Kb = (ushort*)carve((size_t)NTOT * 128 * 2);
  ushort* Vb = (ushort*)carve((size_t)NTOT * 128 * 2);
  float* Keff6 = (float*)carve((size_t)6 * 16384 * 4);
  float* bkeff6 = (float*)carve(6 * 128 * 4);
  ushort* WtHi = (ushort*)carve((size_t)18 * 16384 * 2);
  ushort* WtLo = (ushort*)carve((size_t)18 * 16384 * 2);
  int* cnt = (int*)carve((size_t)2 * NTOT * 4);  // cnt + cursor, one memset
  int* cur = cnt + NTOT;
  int* bsums = (int*)carve(1024 * 4);
  int* rowptr = (int*)carve((NTOT + 1) * 4);
  int* srcs = (int*)carve((size_t)(E0 + E1 + E2) * 4);
  (void)ws_size;

  // ---- initial features (single launch) ----
  k_init_all<<<NTOT / 8, 256, 0, stream>>>(x_in[0], x_in[1], x_in[2], nid[0], nid[1],
                                           nid[2], lin_w, lin_b, emb[0], emb[1], emb[2],
                                           XsA);

  // ---- global CSR over all edge types ----
  {
    const int ETOT = E0 + E1 + E2;
    int nb = (NTOT + 1023) / 1024;
    hipMemsetAsync(cnt, 0, (size_t)2 * NTOT * 4, stream);
    k_count_all<<<(ETOT + 255) / 256, 256, 0, stream>>>(ei[0], ei[1], ei[2], cnt);
    k_blocksum<<<nb, 256, 0, stream>>>(cnt, NTOT, bsums);
    k_scan_bsums<<<1, 256, 0, stream>>>(bsums, nb);
    k_scan_apply<<<nb, 256, 0, stream>>>(cnt, bsums, rowptr, NTOT);
    k_fill_all<<<(ETOT + 255) / 256, 256, 0, stream>>>(ei[0], ei[1], ei[2], rowptr, cur,
                                                       srcs);
  }

  // ---- weight prep (both layers) ----
  {
    dim3 gk(128, 6);
    k_keff<<<gk, 128, 0, stream>>>(qkv_w, qkv_b, W_edge, Keff6, bkeff6);
    dim3 gs(64, 18);
    k_splitw18<<<gs, 256, 0, stream>>>(qkv_w, Keff6, WtHi, WtLo);
  }

  const float scale = 0.08838834764831845f;  // 1/sqrt(128)
  const int GEMM_BLKS = GB0 + GB1 + GB2;
  const int EDGE_BLKS = (NTOT + 3) / 4;

  for (int l = 0; l < 2; ++l) {
    const ushort* Xin = (l == 0) ? XsA : XsB;
    k_gemm3<<<GEMM_BLKS, 256, 0, stream>>>(Xin, WtHi, WtLo, qkv_b, bkeff6, Qb, Kb, Vb, l);
    if (l == 0)
      k_edge<0><<<EDGE_BLKS, 256, 0, stream>>>(rowptr, srcs, Qb, Kb, Vb, XsB,
                                               (float*)nullptr, scale);
    else
      k_edge<1><<<EDGE_BLKS, 256, 0, stream>>>(rowptr, srcs, Qb, Kb, Vb,
                                               (ushort*)nullptr, out, scale);
  }
}

// Round 8
// 505.516 us; speedup vs baseline: 3.6913x; 1.1479x over previous
//
#include <hip/hip_runtime.h>

#define NP 50000
#define NU 100000
#define NS 20000
#define NTOT 170000
#define E0 400000
#define E1 300000
#define E2 300000

typedef _Float16 f16;
typedef __attribute__((ext_vector_type(8))) _Float16 half8;
typedef __attribute__((ext_vector_type(4))) _Float16 half4;
typedef __attribute__((ext_vector_type(4))) float f32x4;
typedef unsigned int uint32;

// ---------------------------------------------------------------------------
// fused init for ALL nodes: 32 threads/node, 4 dims/thread. f16 output.
// ---------------------------------------------------------------------------
__global__ __launch_bounds__(256) void k_init_all(
    const float* __restrict__ xp, const float* __restrict__ xu,
    const float* __restrict__ xs, const int* __restrict__ nidp,
    const int* __restrict__ nidu, const int* __restrict__ nids,
    const float* __restrict__ lin_w, const float* __restrict__ lin_b,
    const float* __restrict__ embp, const float* __restrict__ embu,
    const float* __restrict__ embs, f16* __restrict__ xb) {
  int tid = threadIdx.x;
  int node = blockIdx.x * 8 + (tid >> 5);
  int dg = tid & 31;
  int t, local;
  const float* x;
  const int* nid;
  const float* emb;
  if (node < NP) { t = 0; local = node; x = xp; nid = nidp; emb = embp; }
  else if (node < NP + NU) { t = 1; local = node - NP; x = xu; nid = nidu; emb = embu; }
  else { t = 2; local = node - NP - NU; x = xs; nid = nids; emb = embs; }
  const float* lw = lin_w + t * 20 * 128;
  int d = dg * 4;
  float xv = (dg < 20) ? x[local * 20 + dg] : 0.f;
  float4 s = *(const float4*)&emb[(size_t)nid[local] * 128 + d];
  float4 b = *(const float4*)&lin_b[t * 128 + d];
  s.x += b.x; s.y += b.y; s.z += b.z; s.w += b.w;
#pragma unroll
  for (int j = 0; j < 20; ++j) {
    float xj = __shfl(xv, j, 32);
    float4 w = *(const float4*)&lw[j * 128 + d];
    s.x += xj * w.x; s.y += xj * w.y; s.z += xj * w.z; s.w += xj * w.w;
  }
  half4 o;
  o[0] = (f16)s.x; o[1] = (f16)s.y; o[2] = (f16)s.z; o[3] = (f16)s.w;
  *(half4*)(xb + (size_t)node * 128 + d) = o;
}

// ---------------------------------------------------------------------------
// batched Keff: y = l*3+t.  Keff[y][c][d] = sum_f Wk[c][f] * We[d][f]
// ---------------------------------------------------------------------------
__global__ __launch_bounds__(128) void k_keff(const float* __restrict__ qkv_w,
                                              const float* __restrict__ qkv_b,
                                              const float* __restrict__ W_edge,
                                              float* __restrict__ Keff,
                                              float* __restrict__ bkeff) {
  int y = blockIdx.y;  // l*3 + t
  int l = y / 3, t = y - l * 3;
  int et = (t == 0) ? 0 : (t == 1) ? 2 : 1;  // edge type with dst == t
  const float* Wk = qkv_w + (size_t)(y * 3 + 1) * 16384;
  const float* bk = qkv_b + (size_t)(y * 3 + 1) * 128;
  const float* We = W_edge + (size_t)(l * 3 + et) * 16384;
  float* Ko = Keff + (size_t)y * 16384;
  float* bo = bkeff + (size_t)y * 128;

  __shared__ float Wes[128][65];
  int c = blockIdx.x, tid = threadIdx.x;
  float s = 0.f, tb = 0.f;
  for (int f0 = 0; f0 < 128; f0 += 64) {
    __syncthreads();
    int fr = tid & 63, r0 = tid >> 6;
    for (int it = 0; it < 64; ++it) {
      int row = it * 2 + r0;
      Wes[row][fr] = We[row * 128 + f0 + fr];
    }
    __syncthreads();
#pragma unroll 16
    for (int fp = 0; fp < 64; ++fp) s += Wk[c * 128 + f0 + fp] * Wes[tid][fp];
    if (c == 0) {
      for (int fp = 0; fp < 64; ++fp) tb += bk[f0 + fp] * Wes[tid][fp];
    }
  }
  Ko[c * 128 + tid] = s;
  if (c == 0) bo[tid] = tb;
}

// ---------------------------------------------------------------------------
// split+transpose all 18 weights (f16 hi/lo) in one launch.
// slot s: y=s/3, r=s%3: r0 = Wq[y], r1 = Keff[y], r2 = Wv[y]
// ---------------------------------------------------------------------------
__global__ __launch_bounds__(256) void k_splitw18(const float* __restrict__ qkv_w,
                                                  const float* __restrict__ Keff6,
                                                  f16* __restrict__ hi,
                                                  f16* __restrict__ lo) {
  int slot = blockIdx.y;
  int y = slot / 3, r = slot - y * 3;
  const float* src = (r == 1) ? (Keff6 + (size_t)y * 16384)
                              : (qkv_w + (size_t)(y * 3 + ((r == 0) ? 0 : 2)) * 16384);
  f16* h = hi + (size_t)slot * 16384;
  f16* l = lo + (size_t)slot * 16384;
  int idx = blockIdx.x * 256 + threadIdx.x;  // 0..16383
  int n = idx >> 7, c = idx & 127;
  float f = src[c * 128 + n];
  f16 hb = (f16)f;
  h[idx] = hb;
  l[idx] = (f16)(f - (float)hb);
}

// ---------------------------------------------------------------------------
// Triple-B MFMA GEMM (f16), 64-row tiles, all 3 types in one launch.
// LDS-staged A (swizzled) + LDS-staged epilogue (full-line stores).
// Q/V outputs interleaved per node: QV[node][256] = [Q | V]; K separate.
// ---------------------------------------------------------------------------
#define GB0 782    // ceil(NP/64)
#define GB1 1563   // ceil(NU/64)
#define GB2 313    // ceil(NS/64)
__global__ __launch_bounds__(256, 4) void k_gemm3(
    const f16* __restrict__ Xin,
    const f16* __restrict__ WtHi, const f16* __restrict__ WtLo,
    const float* __restrict__ qkv_b, const float* __restrict__ bkeff6,
    f16* __restrict__ QV, f16* __restrict__ Kb, int l) {
  __shared__ f16 As[64 * 128];  // 16 KB
  __shared__ f16 Ys[64 * 128];  // 16 KB output staging
  int bid = blockIdx.x;
  int t, row0, M, moff;
  if (bid < GB0) { t = 0; row0 = bid * 64; M = NP; moff = 0; }
  else if (bid < GB0 + GB1) { t = 1; row0 = (bid - GB0) * 64; M = NU; moff = NP; }
  else { t = 2; row0 = (bid - GB0 - GB1) * 64; M = NS; moff = NP + NU; }
  int y = l * 3 + t;
  const f16* A = Xin + (size_t)moff * 128;
  const f16* Whi = WtHi + (size_t)y * 3 * 16384;
  const f16* Wlo = WtLo + (size_t)y * 3 * 16384;

  int tid = threadIdx.x;
  int wave = tid >> 6, lane = tid & 63;
  int colw = wave * 32;
  int lrow = lane & 15, kgrp = lane >> 4;

  // ---- stage A tile: linear global read, swizzled LDS write ----
#pragma unroll
  for (int i = 0; i < 4; ++i) {
    int chunkLin = i * 256 + tid;  // 0..1023
    int row = chunkLin >> 4;
    int chunk = chunkLin & 15;
    int grow = row0 + row;
    if (grow >= M) grow = M - 1;
    half8 v = *(const half8*)(A + (size_t)grow * 128 + chunk * 8);
    *(half8*)(As + row * 128 + (chunk ^ (row & 7)) * 8) = v;
  }
  __syncthreads();

  int x7 = lrow & 7;

  for (int bw = 0; bw < 3; ++bw) {
    f32x4 acc[4][2] = {};
#pragma unroll
    for (int s = 0; s < 4; ++s) {
      half8 bh[2], bl[2];
#pragma unroll
      for (int nt = 0; nt < 2; ++nt) {
        int col = colw + nt * 16 + lrow;
        size_t boff = (size_t)bw * 16384 + col * 128 + s * 32 + kgrp * 8;
        bh[nt] = *(const half8*)(Whi + boff);
        bl[nt] = *(const half8*)(Wlo + boff);
      }
      int c2 = (s * 4 + kgrp) ^ x7;
#pragma unroll
      for (int mt = 0; mt < 4; ++mt) {
        int row = mt * 16 + lrow;
        half8 a = *(const half8*)(As + row * 128 + c2 * 8);
        acc[mt][0] = __builtin_amdgcn_mfma_f32_16x16x32_f16(a, bh[0], acc[mt][0], 0, 0, 0);
        acc[mt][0] = __builtin_amdgcn_mfma_f32_16x16x32_f16(a, bl[0], acc[mt][0], 0, 0, 0);
        acc[mt][1] = __builtin_amdgcn_mfma_f32_16x16x32_f16(a, bh[1], acc[mt][1], 0, 0, 0);
        acc[mt][1] = __builtin_amdgcn_mfma_f32_16x16x32_f16(a, bl[1], acc[mt][1], 0, 0, 0);
      }
    }
    // ---- epilogue: stage through LDS (swizzled), stream full lines ----
    const float* bias = (bw == 0) ? (qkv_b + (size_t)(y * 3 + 0) * 128)
                      : (bw == 1) ? (bkeff6 + (size_t)y * 128)
                                  : (qkv_b + (size_t)(y * 3 + 2) * 128);
    f16* Ybase = (bw == 1) ? Kb : (QV + ((bw == 2) ? 128 : 0));
    int RS = (bw == 1) ? 128 : 256;
    float b0 = bias[colw + lrow];
    float b1 = bias[colw + 16 + lrow];
    int col0i = colw + lrow;
    int col1i = colw + 16 + lrow;
    __syncthreads();
#pragma unroll
    for (int mt = 0; mt < 4; ++mt) {
#pragma unroll
      for (int r = 0; r < 4; ++r) {
        int lr = mt * 16 + kgrp * 4 + r;
        int sw = lr & 7;
        Ys[lr * 128 + (((col0i >> 3) ^ sw) * 8) + (col0i & 7)] = (f16)(acc[mt][0][r] + b0);
        Ys[lr * 128 + (((col1i >> 3) ^ sw) * 8) + (col1i & 7)] = (f16)(acc[mt][1][r] + b1);
      }
    }
    __syncthreads();
#pragma unroll
    for (int i = 0; i < 4; ++i) {
      int chunk = i * 256 + tid;  // 0..1023
      int row = chunk >> 4, c = chunk & 15;
      int grow = row0 + row;
      if (grow < M)
        *(half8*)(Ybase + (size_t)(moff + grow) * RS + c * 8) =
            *(const half8*)(Ys + row * 128 + ((c ^ (row & 7)) * 8));
    }
  }
}

// ---------------------------------------------------------------------------
// FUSED edge kernel v3: 16 lanes per dst row (4 rows/wave), 8 dims/lane,
// edges serial. Dims partitioned -> no accumulator reduction; dsum identical
// across the 16 lanes for free. QV interleaved gathers (512B/node block).
// rows [0,50k)=et0 dst proxy, [50k,70k)=et1 dst server, [70k,170k)=et2 dst user
// ---------------------------------------------------------------------------
template <int MODE>
__global__ __launch_bounds__(256) void k_edge(
    const int* __restrict__ rowptr, const int* __restrict__ srcs,
    const f16* __restrict__ QV, const f16* __restrict__ Kb,
    f16* __restrict__ obf, float* __restrict__ of, float scale) {
  int gid = blockIdx.x * 256 + threadIdx.x;
  int wid = gid >> 4;  // dst row, one per 16-lane group
  if (wid >= NTOT) return;
  int sub = threadIdx.x & 15;  // dims sub*8 .. sub*8+7
  int dstNode, srcBase;
  if (wid < NP) { dstNode = wid; srcBase = NP; }
  else if (wid < NP + NS) { dstNode = wid + 100000; srcBase = 0; }
  else { dstNode = wid - NS; srcBase = NP + NU; }

  int s0 = rowptr[wid], s1 = rowptr[wid + 1];

  float kf[8];
  {
    half8 kh = *(const half8*)(Kb + (size_t)dstNode * 128 + sub * 8);
#pragma unroll
    for (int j = 0; j < 8; ++j) kf[j] = (float)kh[j];
  }

  float acc[8] = {};
  float dsum = 0.f;
  for (int k = s0; k < s1; ++k) {
    int src = srcBase + srcs[k];
    const f16* qv = QV + (size_t)src * 256 + sub * 8;
    half8 qh = *(const half8*)qv;
    half8 vh = *(const half8*)(qv + 128);
    float p = 0.f;
#pragma unroll
    for (int j = 0; j < 8; ++j) p = fmaf((float)qh[j], kf[j], p);
    p += __shfl_xor(p, 8, 16);
    p += __shfl_xor(p, 4, 16);
    p += __shfl_xor(p, 2, 16);
    p += __shfl_xor(p, 1, 16);
    float s = p * scale;
    s = (s > 0.f) ? s : 0.01f * s;
    float e = __expf(s);
    dsum += e;
#pragma unroll
    for (int j = 0; j < 8; ++j) acc[j] = fmaf((float)vh[j], e, acc[j]);
  }

  float inv = (s1 > s0) ? 1.f / dsum : 0.f;

  if (MODE == 0) {
    half8 o;
#pragma unroll
    for (int j = 0; j < 8; ++j) o[j] = (f16)fmaxf(acc[j] * inv, 0.f);
    *(half8*)(obf + (size_t)dstNode * 128 + sub * 8) = o;
  } else {
    float4 w0, w1;
    w0.x = acc[0] * inv; w0.y = acc[1] * inv; w0.z = acc[2] * inv; w0.w = acc[3] * inv;
    w1.x = acc[4] * inv; w1.y = acc[5] * inv; w1.z = acc[6] * inv; w1.w = acc[7] * inv;
    float* orow = of + (size_t)dstNode * 128 + sub * 8;
    *(float4*)orow = w0;
    *(float4*)(orow + 4) = w1;
  }
}

// ---------------------------------------------------------------------------
// global CSR build over all 3 edge types
// ---------------------------------------------------------------------------
__global__ void k_count_all(const int* __restrict__ e0, const int* __restrict__ e1,
                            const int* __restrict__ e2, int* __restrict__ cnt) {
  int e = blockIdx.x * 256 + threadIdx.x;
  if (e < E0) atomicAdd(&cnt[e0[E0 + e]], 1);
  else if (e < E0 + E1) atomicAdd(&cnt[NP + e1[E1 + (e - E0)]], 1);
  else if (e < E0 + E1 + E2) atomicAdd(&cnt[NP + NS + e2[E2 + (e - E0 - E1)]], 1);
}

__global__ void k_fill_all(const int* __restrict__ e0, const int* __restrict__ e1,
                           const int* __restrict__ e2, const int* __restrict__ rowptr,
                           int* __restrict__ cur, int* __restrict__ srcs) {
  int e = blockIdx.x * 256 + threadIdx.x;
  int row, src;
  if (e < E0) { row = e0[E0 + e]; src = e0[e]; }
  else if (e < E0 + E1) { row = NP + e1[E1 + (e - E0)]; src = e1[e - E0]; }
  else if (e < E0 + E1 + E2) { row = NP + NS + e2[E2 + (e - E0 - E1)]; src = e2[e - E0 - E1]; }
  else return;
  int p = atomicAdd(&cur[row], 1);
  srcs[rowptr[row] + p] = src;
}

__global__ __launch_bounds__(256) void k_blocksum(const int* __restrict__ c, int N,
                                                  int* __restrict__ bs) {
  int base = blockIdx.x * 1024;
  int t = threadIdx.x;
  int s = 0;
#pragma unroll
  for (int j = 0; j < 4; ++j) {
    int i = base + t * 4 + j;
    if (i < N) s += c[i];
  }
#pragma unroll
  for (int off = 32; off; off >>= 1) s += __shfl_down(s, off, 64);
  __shared__ int wsm[4];
  if ((t & 63) == 0) wsm[t >> 6] = s;
  __syncthreads();
  if (t == 0) bs[blockIdx.x] = wsm[0] + wsm[1] + wsm[2] + wsm[3];
}

__global__ __launch_bounds__(256) void k_scan_bsums(int* __restrict__ bs, int nb) {
  __shared__ int sm[256];
  int t = threadIdx.x;
  int v[4];
  int s = 0;
#pragma unroll
  for (int j = 0; j < 4; ++j) {
    int i = t * 4 + j;
    v[j] = (i < nb) ? bs[i] : 0;
    s += v[j];
  }
  sm[t] = s;
  __syncthreads();
  for (int off = 1; off < 256; off <<= 1) {
    int x = (t >= off) ? sm[t - off] : 0;
    __syncthreads();
    sm[t] += x;
    __syncthreads();
  }
  int run = t ? sm[t - 1] : 0;
#pragma unroll
  for (int j = 0; j < 4; ++j) {
    int i = t * 4 + j;
    if (i < nb) {
      int tmp = v[j];
      bs[i] = run;
      run += tmp;
    }
  }
}

__global__ __launch_bounds__(256) void k_scan_apply(const int* __restrict__ c,
                                                    const int* __restrict__ bofs,
                                                    int* __restrict__ rowptr, int N) {
  __shared__ int sm[256];
  int base = blockIdx.x * 1024, t = threadIdx.x;
  int v[4];
  int s = 0;
#pragma unroll
  for (int j = 0; j < 4; ++j) {
    int i = base + t * 4 + j;
    v[j] = (i < N) ? c[i] : 0;
    s += v[j];
  }
  sm[t] = s;
  __syncthreads();
  for (int off = 1; off < 256; off <<= 1) {
    int x = (t >= off) ? sm[t - off] : 0;
    __syncthreads();
    sm[t] += x;
    __syncthreads();
  }
  int run = bofs[blockIdx.x] + (t ? sm[t - 1] : 0);
#pragma unroll
  for (int j = 0; j < 4; ++j) {
    int i = base + t * 4 + j;
    if (i < N) {
      run += v[j];
      rowptr[i + 1] = run;
    }
  }
  if (blockIdx.x == 0 && t == 0) rowptr[0] = 0;
}

// ---------------------------------------------------------------------------

extern "C" void kernel_launch(void* const* d_in, const int* in_sizes, int n_in,
                              void* d_out, int out_size, void* d_ws, size_t ws_size,
                              hipStream_t stream) {
  const float* x_in[3] = {(const float*)d_in[0], (const float*)d_in[1], (const float*)d_in[2]};
  const int* nid[3] = {(const int*)d_in[3], (const int*)d_in[4], (const int*)d_in[5]};
  const int* ei[3] = {(const int*)d_in[6], (const int*)d_in[7], (const int*)d_in[8]};
  const float* lin_w = (const float*)d_in[9];
  const float* lin_b = (const float*)d_in[10];
  const float* emb[3] = {(const float*)d_in[11], (const float*)d_in[12], (const float*)d_in[13]};
  const float* qkv_w = (const float*)d_in[14];
  const float* qkv_b = (const float*)d_in[15];
  const float* W_edge = (const float*)d_in[16];
  float* out = (float*)d_out;

  char* ws = (char*)d_ws;
  size_t o = 0;
  auto carve = [&](size_t bytes) {
    char* p = ws + o;
    o = (o + bytes + 255) & ~(size_t)255;
    return p;
  };
  f16* XsA = (f16*)carve((size_t)NTOT * 128 * 2);
  f16* XsB = (f16*)carve((size_t)NTOT * 128 * 2);
  f16* QV = (f16*)carve((size_t)NTOT * 256 * 2);   // interleaved [Q|V] per node
  f16* Kb = (f16*)carve((size_t)NTOT * 128 * 2);
  float* Keff6 = (float*)carve((size_t)6 * 16384 * 4);
  float* bkeff6 = (float*)carve(6 * 128 * 4);
  f16* WtHi = (f16*)carve((size_t)18 * 16384 * 2);
  f16* WtLo = (f16*)carve((size_t)18 * 16384 * 2);
  int* cnt = (int*)carve((size_t)2 * NTOT * 4);  // cnt + cursor, one memset
  int* cur = cnt + NTOT;
  int* bsums = (int*)carve(1024 * 4);
  int* rowptr = (int*)carve((NTOT + 1) * 4);
  int* srcs = (int*)carve((size_t)(E0 + E1 + E2) * 4);
  (void)ws_size;

  // ---- initial features (single launch) ----
  k_init_all<<<NTOT / 8, 256, 0, stream>>>(x_in[0], x_in[1], x_in[2], nid[0], nid[1],
                                           nid[2], lin_w, lin_b, emb[0], emb[1], emb[2],
                                           XsA);

  // ---- global CSR over all edge types ----
  {
    const int ETOT = E0 + E1 + E2;
    int nb = (NTOT + 1023) / 1024;
    hipMemsetAsync(cnt, 0, (size_t)2 * NTOT * 4, stream);
    k_count_all<<<(ETOT + 255) / 256, 256, 0, stream>>>(ei[0], ei[1], ei[2], cnt);
    k_blocksum<<<nb, 256, 0, stream>>>(cnt, NTOT, bsums);
    k_scan_bsums<<<1, 256, 0, stream>>>(bsums, nb);
    k_scan_apply<<<nb, 256, 0, stream>>>(cnt, bsums, rowptr, NTOT);
    k_fill_all<<<(ETOT + 255) / 256, 256, 0, stream>>>(ei[0], ei[1], ei[2], rowptr, cur,
                                                       srcs);
  }

  // ---- weight prep (both layers) ----
  {
    dim3 gk(128, 6);
    k_keff<<<gk, 128, 0, stream>>>(qkv_w, qkv_b, W_edge, Keff6, bkeff6);
    dim3 gs(64, 18);
    k_splitw18<<<gs, 256, 0, stream>>>(qkv_w, Keff6, WtHi, WtLo);
  }

  const float scale = 0.08838834764831845f;  // 1/sqrt(128)
  const int GEMM_BLKS = GB0 + GB1 + GB2;
  const int EDGE_BLKS = (NTOT * 16 + 255) / 256;

  for (int l = 0; l < 2; ++l) {
    const f16* Xin = (l == 0) ? XsA : XsB;
    k_gemm3<<<GEMM_BLKS, 256, 0, stream>>>(Xin, WtHi, WtLo, qkv_b, bkeff6, QV, Kb, l);
    if (l == 0)
      k_edge<0><<<EDGE_BLKS, 256, 0, stream>>>(rowptr, srcs, QV, Kb, XsB,
                                               (float*)nullptr, scale);
    else
      k_edge<1><<<EDGE_BLKS, 256, 0, stream>>>(rowptr, srcs, QV, Kb,
                                               (f16*)nullptr, out, scale);
  }
}

// Round 9
// 472.439 us; speedup vs baseline: 3.9497x; 1.0700x over previous
//
#include <hip/hip_runtime.h>

#define NP 50000
#define NU 100000
#define NS 20000
#define NTOT 170000
#define E0 400000
#define E1 300000
#define E2 300000

typedef _Float16 f16;
typedef __attribute__((ext_vector_type(8))) _Float16 half8;
typedef __attribute__((ext_vector_type(4))) _Float16 half4;
typedef __attribute__((ext_vector_type(4))) float f32x4;
typedef unsigned int uint32;

// ---------------------------------------------------------------------------
// fused init v2: block = 64 nodes (type-pure ranges), thread = 4 dims x 8
// nodes; lin_w held in registers (20 x float4), x staged via LDS (broadcast).
// ---------------------------------------------------------------------------
#define IB0 782    // ceil(NP/64)
#define IB1 1563   // ceil(NU/64)
#define IB2 313    // ceil(NS/64)
__global__ __launch_bounds__(256) void k_init_all(
    const float* __restrict__ xp, const float* __restrict__ xu,
    const float* __restrict__ xs, const int* __restrict__ nidp,
    const int* __restrict__ nidu, const int* __restrict__ nids,
    const float* __restrict__ lin_w, const float* __restrict__ lin_b,
    const float* __restrict__ embp, const float* __restrict__ embu,
    const float* __restrict__ embs, f16* __restrict__ xb) {
  __shared__ float xl[64 * 20];  // 5 KB
  int bid = blockIdx.x, tid = threadIdx.x;
  int t, base, M, goff;
  const float* x;
  const int* nid;
  const float* emb;
  if (bid < IB0) { t = 0; base = bid * 64; M = NP; goff = 0; x = xp; nid = nidp; emb = embp; }
  else if (bid < IB0 + IB1) { t = 1; base = (bid - IB0) * 64; M = NU; goff = NP; x = xu; nid = nidu; emb = embu; }
  else { t = 2; base = (bid - IB0 - IB1) * 64; M = NS; goff = NP + NU; x = xs; nid = nids; emb = embs; }

  // stage x rows for the block's 64 nodes
#pragma unroll
  for (int i = 0; i < 5; ++i) {
    int idx = i * 256 + tid;  // 0..1279
    int nn = idx / 20, jj = idx - nn * 20;
    int gn = base + nn;
    if (gn >= M) gn = M - 1;
    xl[idx] = x[gn * 20 + jj];
  }
  __syncthreads();

  int dg = tid & 31, ns = tid >> 5;
  int d = dg * 4;
  const float* lw = lin_w + t * 20 * 128 + d;
  float4 w[20];
#pragma unroll
  for (int j = 0; j < 20; ++j) w[j] = *(const float4*)(lw + j * 128);
  float4 bb = *(const float4*)&lin_b[t * 128 + d];

#pragma unroll 2
  for (int i = 0; i < 8; ++i) {
    int ln = i * 8 + ns;
    int gn = base + ln;
    bool ok = gn < M;
    int gnc = ok ? gn : M - 1;
    float4 s = *(const float4*)&emb[(size_t)nid[gnc] * 128 + d];
    s.x += bb.x; s.y += bb.y; s.z += bb.z; s.w += bb.w;
#pragma unroll
    for (int j = 0; j < 20; ++j) {
      float xj = xl[ln * 20 + j];
      s.x += xj * w[j].x; s.y += xj * w[j].y; s.z += xj * w[j].z; s.w += xj * w[j].w;
    }
    if (ok) {
      half4 o;
      o[0] = (f16)s.x; o[1] = (f16)s.y; o[2] = (f16)s.z; o[3] = (f16)s.w;
      *(half4*)(xb + (size_t)(goff + gn) * 128 + d) = o;
    }
  }
}

// ---------------------------------------------------------------------------
// batched Keff: y = l*3+t.  Keff[y][c][d] = sum_f Wk[c][f] * We[d][f]
// ---------------------------------------------------------------------------
__global__ __launch_bounds__(128) void k_keff(const float* __restrict__ qkv_w,
                                              const float* __restrict__ qkv_b,
                                              const float* __restrict__ W_edge,
                                              float* __restrict__ Keff,
                                              float* __restrict__ bkeff) {
  int y = blockIdx.y;  // l*3 + t
  int l = y / 3, t = y - l * 3;
  int et = (t == 0) ? 0 : (t == 1) ? 2 : 1;  // edge type with dst == t
  const float* Wk = qkv_w + (size_t)(y * 3 + 1) * 16384;
  const float* bk = qkv_b + (size_t)(y * 3 + 1) * 128;
  const float* We = W_edge + (size_t)(l * 3 + et) * 16384;
  float* Ko = Keff + (size_t)y * 16384;
  float* bo = bkeff + (size_t)y * 128;

  __shared__ float Wes[128][65];
  int c = blockIdx.x, tid = threadIdx.x;
  float s = 0.f, tb = 0.f;
  for (int f0 = 0; f0 < 128; f0 += 64) {
    __syncthreads();
    int fr = tid & 63, r0 = tid >> 6;
    for (int it = 0; it < 64; ++it) {
      int row = it * 2 + r0;
      Wes[row][fr] = We[row * 128 + f0 + fr];
    }
    __syncthreads();
#pragma unroll 16
    for (int fp = 0; fp < 64; ++fp) s += Wk[c * 128 + f0 + fp] * Wes[tid][fp];
    if (c == 0) {
      for (int fp = 0; fp < 64; ++fp) tb += bk[f0 + fp] * Wes[tid][fp];
    }
  }
  Ko[c * 128 + tid] = s;
  if (c == 0) bo[tid] = tb;
}

// ---------------------------------------------------------------------------
// split+transpose all 18 weights (f16 hi/lo) in one launch.
// ---------------------------------------------------------------------------
__global__ __launch_bounds__(256) void k_splitw18(const float* __restrict__ qkv_w,
                                                  const float* __restrict__ Keff6,
                                                  f16* __restrict__ hi,
                                                  f16* __restrict__ lo) {
  int slot = blockIdx.y;
  int y = slot / 3, r = slot - y * 3;
  const float* src = (r == 1) ? (Keff6 + (size_t)y * 16384)
                              : (qkv_w + (size_t)(y * 3 + ((r == 0) ? 0 : 2)) * 16384);
  f16* h = hi + (size_t)slot * 16384;
  f16* l = lo + (size_t)slot * 16384;
  int idx = blockIdx.x * 256 + threadIdx.x;  // 0..16383
  int n = idx >> 7, c = idx & 127;
  float f = src[c * 128 + n];
  f16 hb = (f16)f;
  h[idx] = hb;
  l[idx] = (f16)(f - (float)hb);
}

// ---------------------------------------------------------------------------
// Triple-B MFMA GEMM (f16), 64-row tiles, all 3 types in one launch.
// LDS-staged A (swizzled) + LDS-staged epilogue (full-line stores).
// Q/V outputs interleaved per node: QV[node][256] = [Q | V]; K separate.
// ---------------------------------------------------------------------------
#define GB0 782    // ceil(NP/64)
#define GB1 1563   // ceil(NU/64)
#define GB2 313    // ceil(NS/64)
__global__ __launch_bounds__(256, 4) void k_gemm3(
    const f16* __restrict__ Xin,
    const f16* __restrict__ WtHi, const f16* __restrict__ WtLo,
    const float* __restrict__ qkv_b, const float* __restrict__ bkeff6,
    f16* __restrict__ QV, f16* __restrict__ Kb, int l) {
  __shared__ f16 As[64 * 128];  // 16 KB
  __shared__ f16 Ys[64 * 128];  // 16 KB output staging
  int bid = blockIdx.x;
  int t, row0, M, moff;
  if (bid < GB0) { t = 0; row0 = bid * 64; M = NP; moff = 0; }
  else if (bid < GB0 + GB1) { t = 1; row0 = (bid - GB0) * 64; M = NU; moff = NP; }
  else { t = 2; row0 = (bid - GB0 - GB1) * 64; M = NS; moff = NP + NU; }
  int y = l * 3 + t;
  const f16* A = Xin + (size_t)moff * 128;
  const f16* Whi = WtHi + (size_t)y * 3 * 16384;
  const f16* Wlo = WtLo + (size_t)y * 3 * 16384;

  int tid = threadIdx.x;
  int wave = tid >> 6, lane = tid & 63;
  int colw = wave * 32;
  int lrow = lane & 15, kgrp = lane >> 4;

  // ---- stage A tile: linear global read, swizzled LDS write ----
#pragma unroll
  for (int i = 0; i < 4; ++i) {
    int chunkLin = i * 256 + tid;  // 0..1023
    int row = chunkLin >> 4;
    int chunk = chunkLin & 15;
    int grow = row0 + row;
    if (grow >= M) grow = M - 1;
    half8 v = *(const half8*)(A + (size_t)grow * 128 + chunk * 8);
    *(half8*)(As + row * 128 + (chunk ^ (row & 7)) * 8) = v;
  }
  __syncthreads();

  int x7 = lrow & 7;

  for (int bw = 0; bw < 3; ++bw) {
    f32x4 acc[4][2] = {};
#pragma unroll
    for (int s = 0; s < 4; ++s) {
      half8 bh[2], bl[2];
#pragma unroll
      for (int nt = 0; nt < 2; ++nt) {
        int col = colw + nt * 16 + lrow;
        size_t boff = (size_t)bw * 16384 + col * 128 + s * 32 + kgrp * 8;
        bh[nt] = *(const half8*)(Whi + boff);
        bl[nt] = *(const half8*)(Wlo + boff);
      }
      int c2 = (s * 4 + kgrp) ^ x7;
#pragma unroll
      for (int mt = 0; mt < 4; ++mt) {
        int row = mt * 16 + lrow;
        half8 a = *(const half8*)(As + row * 128 + c2 * 8);
        acc[mt][0] = __builtin_amdgcn_mfma_f32_16x16x32_f16(a, bh[0], acc[mt][0], 0, 0, 0);
        acc[mt][0] = __builtin_amdgcn_mfma_f32_16x16x32_f16(a, bl[0], acc[mt][0], 0, 0, 0);
        acc[mt][1] = __builtin_amdgcn_mfma_f32_16x16x32_f16(a, bh[1], acc[mt][1], 0, 0, 0);
        acc[mt][1] = __builtin_amdgcn_mfma_f32_16x16x32_f16(a, bl[1], acc[mt][1], 0, 0, 0);
      }
    }
    // ---- epilogue: stage through LDS (swizzled), stream full lines ----
    const float* bias = (bw == 0) ? (qkv_b + (size_t)(y * 3 + 0) * 128)
                      : (bw == 1) ? (bkeff6 + (size_t)y * 128)
                                  : (qkv_b + (size_t)(y * 3 + 2) * 128);
    f16* Ybase = (bw == 1) ? Kb : (QV + ((bw == 2) ? 128 : 0));
    int RS = (bw == 1) ? 128 : 256;
    float b0 = bias[colw + lrow];
    float b1 = bias[colw + 16 + lrow];
    int col0i = colw + lrow;
    int col1i = colw + 16 + lrow;
    __syncthreads();
#pragma unroll
    for (int mt = 0; mt < 4; ++mt) {
#pragma unroll
      for (int r = 0; r < 4; ++r) {
        int lr = mt * 16 + kgrp * 4 + r;
        int sw = lr & 7;
        Ys[lr * 128 + (((col0i >> 3) ^ sw) * 8) + (col0i & 7)] = (f16)(acc[mt][0][r] + b0);
        Ys[lr * 128 + (((col1i >> 3) ^ sw) * 8) + (col1i & 7)] = (f16)(acc[mt][1][r] + b1);
      }
    }
    __syncthreads();
#pragma unroll
    for (int i = 0; i < 4; ++i) {
      int chunk = i * 256 + tid;  // 0..1023
      int row = chunk >> 4, c = chunk & 15;
      int grow = row0 + row;
      if (grow < M)
        *(half8*)(Ybase + (size_t)(moff + grow) * RS + c * 8) =
            *(const half8*)(Ys + row * 128 + ((c ^ (row & 7)) * 8));
    }
  }
}

// ---------------------------------------------------------------------------
// FUSED edge kernel: 16 lanes per dst row (4 rows/wave), 8 dims/lane,
// edges serial with depth-1 prefetch. Dims partitioned -> no accumulator
// reduction. QV interleaved gathers (512B/node block).
// ---------------------------------------------------------------------------
template <int MODE>
__global__ __launch_bounds__(256) void k_edge(
    const int* __restrict__ rowptr, const int* __restrict__ srcs,
    const f16* __restrict__ QV, const f16* __restrict__ Kb,
    f16* __restrict__ obf, float* __restrict__ of, float scale) {
  int gid = blockIdx.x * 256 + threadIdx.x;
  int wid = gid >> 4;  // dst row, one per 16-lane group
  if (wid >= NTOT) return;
  int sub = threadIdx.x & 15;  // dims sub*8 .. sub*8+7
  int dstNode, srcBase;
  if (wid < NP) { dstNode = wid; srcBase = NP; }
  else if (wid < NP + NS) { dstNode = wid + 100000; srcBase = 0; }
  else { dstNode = wid - NS; srcBase = NP + NU; }

  int s0 = rowptr[wid], s1 = rowptr[wid + 1];

  float kf[8];
  {
    half8 kh = *(const half8*)(Kb + (size_t)dstNode * 128 + sub * 8);
#pragma unroll
    for (int j = 0; j < 8; ++j) kf[j] = (float)kh[j];
  }

  float acc[8] = {};
  float dsum = 0.f;
  int k = s0;
  half8 qN, vN;
  if (k < s1) {
    const f16* qv = QV + (size_t)(srcBase + srcs[k]) * 256 + sub * 8;
    qN = *(const half8*)qv;
    vN = *(const half8*)(qv + 128);
  }
  while (k < s1) {
    half8 qh = qN, vh = vN;
    int kn = k + 1;
    if (kn < s1) {
      const f16* qv = QV + (size_t)(srcBase + srcs[kn]) * 256 + sub * 8;
      qN = *(const half8*)qv;
      vN = *(const half8*)(qv + 128);
    }
    float p = 0.f;
#pragma unroll
    for (int j = 0; j < 8; ++j) p = fmaf((float)qh[j], kf[j], p);
    p += __shfl_xor(p, 8, 16);
    p += __shfl_xor(p, 4, 16);
    p += __shfl_xor(p, 2, 16);
    p += __shfl_xor(p, 1, 16);
    float s = p * scale;
    s = (s > 0.f) ? s : 0.01f * s;
    float e = __expf(s);
    dsum += e;
#pragma unroll
    for (int j = 0; j < 8; ++j) acc[j] = fmaf((float)vh[j], e, acc[j]);
    k = kn;
  }

  float inv = (s1 > s0) ? 1.f / dsum : 0.f;

  if (MODE == 0) {
    half8 o;
#pragma unroll
    for (int j = 0; j < 8; ++j) o[j] = (f16)fmaxf(acc[j] * inv, 0.f);
    *(half8*)(obf + (size_t)dstNode * 128 + sub * 8) = o;
  } else {
    float4 w0, w1;
    w0.x = acc[0] * inv; w0.y = acc[1] * inv; w0.z = acc[2] * inv; w0.w = acc[3] * inv;
    w1.x = acc[4] * inv; w1.y = acc[5] * inv; w1.z = acc[6] * inv; w1.w = acc[7] * inv;
    float* orow = of + (size_t)dstNode * 128 + sub * 8;
    *(float4*)orow = w0;
    *(float4*)(orow + 4) = w1;
  }
}

// ---------------------------------------------------------------------------
// global CSR build over all 3 edge types
// ---------------------------------------------------------------------------
__global__ void k_count_all(const int* __restrict__ e0, const int* __restrict__ e1,
                            const int* __restrict__ e2, int* __restrict__ cnt) {
  int e = blockIdx.x * 256 + threadIdx.x;
  if (e < E0) atomicAdd(&cnt[e0[E0 + e]], 1);
  else if (e < E0 + E1) atomicAdd(&cnt[NP + e1[E1 + (e - E0)]], 1);
  else if (e < E0 + E1 + E2) atomicAdd(&cnt[NP + NS + e2[E2 + (e - E0 - E1)]], 1);
}

__global__ void k_fill_all(const int* __restrict__ e0, const int* __restrict__ e1,
                           const int* __restrict__ e2, const int* __restrict__ rowptr,
                           int* __restrict__ cur, int* __restrict__ srcs) {
  int e = blockIdx.x * 256 + threadIdx.x;
  int row, src;
  if (e < E0) { row = e0[E0 + e]; src = e0[e]; }
  else if (e < E0 + E1) { row = NP + e1[E1 + (e - E0)]; src = e1[e - E0]; }
  else if (e < E0 + E1 + E2) { row = NP + NS + e2[E2 + (e - E0 - E1)]; src = e2[e - E0 - E1]; }
  else return;
  int p = atomicAdd(&cur[row], 1);
  srcs[rowptr[row] + p] = src;
}

__global__ __launch_bounds__(256) void k_blocksum(const int* __restrict__ c, int N,
                                                  int* __restrict__ bs) {
  int base = blockIdx.x * 1024;
  int t = threadIdx.x;
  int s = 0;
#pragma unroll
  for (int j = 0; j < 4; ++j) {
    int i = base + t * 4 + j;
    if (i < N) s += c[i];
  }
#pragma unroll
  for (int off = 32; off; off >>= 1) s += __shfl_down(s, off, 64);
  __shared__ int wsm[4];
  if ((t & 63) == 0) wsm[t >> 6] = s;
  __syncthreads();
  if (t == 0) bs[blockIdx.x] = wsm[0] + wsm[1] + wsm[2] + wsm[3];
}

__global__ __launch_bounds__(256) void k_scan_bsums(int* __restrict__ bs, int nb) {
  __shared__ int sm[256];
  int t = threadIdx.x;
  int v[4];
  int s = 0;
#pragma unroll
  for (int j = 0; j < 4; ++j) {
    int i = t * 4 + j;
    v[j] = (i < nb) ? bs[i] : 0;
    s += v[j];
  }
  sm[t] = s;
  __syncthreads();
  for (int off = 1; off < 256; off <<= 1) {
    int x = (t >= off) ? sm[t - off] : 0;
    __syncthreads();
    sm[t] += x;
    __syncthreads();
  }
  int run = t ? sm[t - 1] : 0;
#pragma unroll
  for (int j = 0; j < 4; ++j) {
    int i = t * 4 + j;
    if (i < nb) {
      int tmp = v[j];
      bs[i] = run;
      run += tmp;
    }
  }
}

__global__ __launch_bounds__(256) void k_scan_apply(const int* __restrict__ c,
                                                    const int* __restrict__ bofs,
                                                    int* __restrict__ rowptr, int N) {
  __shared__ int sm[256];
  int base = blockIdx.x * 1024, t = threadIdx.x;
  int v[4];
  int s = 0;
#pragma unroll
  for (int j = 0; j < 4; ++j) {
    int i = base + t * 4 + j;
    v[j] = (i < N) ? c[i] : 0;
    s += v[j];
  }
  sm[t] = s;
  __syncthreads();
  for (int off = 1; off < 256; off <<= 1) {
    int x = (t >= off) ? sm[t - off] : 0;
    __syncthreads();
    sm[t] += x;
    __syncthreads();
  }
  int run = bofs[blockIdx.x] + (t ? sm[t - 1] : 0);
#pragma unroll
  for (int j = 0; j < 4; ++j) {
    int i = base + t * 4 + j;
    if (i < N) {
      run += v[j];
      rowptr[i + 1] = run;
    }
  }
  if (blockIdx.x == 0 && t == 0) rowptr[0] = 0;
}

// ---------------------------------------------------------------------------

extern "C" void kernel_launch(void* const* d_in, const int* in_sizes, int n_in,
                              void* d_out, int out_size, void* d_ws, size_t ws_size,
                              hipStream_t stream) {
  const float* x_in[3] = {(const float*)d_in[0], (const float*)d_in[1], (const float*)d_in[2]};
  const int* nid[3] = {(const int*)d_in[3], (const int*)d_in[4], (const int*)d_in[5]};
  const int* ei[3] = {(const int*)d_in[6], (const int*)d_in[7], (const int*)d_in[8]};
  const float* lin_w = (const float*)d_in[9];
  const float* lin_b = (const float*)d_in[10];
  const float* emb[3] = {(const float*)d_in[11], (const float*)d_in[12], (const float*)d_in[13]};
  const float* qkv_w = (const float*)d_in[14];
  const float* qkv_b = (const float*)d_in[15];
  const float* W_edge = (const float*)d_in[16];
  float* out = (float*)d_out;

  char* ws = (char*)d_ws;
  size_t o = 0;
  auto carve = [&](size_t bytes) {
    char* p = ws + o;
    o = (o + bytes + 255) & ~(size_t)255;
    return p;
  };
  f16* XsA = (f16*)carve((size_t)NTOT * 128 * 2);
  f16* XsB = (f16*)carve((size_t)NTOT * 128 * 2);
  f16* QV = (f16*)carve((size_t)NTOT * 256 * 2);   // interleaved [Q|V] per node
  f16* Kb = (f16*)carve((size_t)NTOT * 128 * 2);
  float* Keff6 = (float*)carve((size_t)6 * 16384 * 4);
  float* bkeff6 = (float*)carve(6 * 128 * 4);
  f16* WtHi = (f16*)carve((size_t)18 * 16384 * 2);
  f16* WtLo = (f16*)carve((size_t)18 * 16384 * 2);
  int* cnt = (int*)carve((size_t)2 * NTOT * 4);  // cnt + cursor, one memset
  int* cur = cnt + NTOT;
  int* bsums = (int*)carve(1024 * 4);
  int* rowptr = (int*)carve((NTOT + 1) * 4);
  int* srcs = (int*)carve((size_t)(E0 + E1 + E2) * 4);
  (void)ws_size;

  // ---- initial features (single launch, w-amortized) ----
  k_init_all<<<IB0 + IB1 + IB2, 256, 0, stream>>>(
      x_in[0], x_in[1], x_in[2], nid[0], nid[1], nid[2], lin_w, lin_b, emb[0],
      emb[1], emb[2], XsA);

  // ---- global CSR over all edge types ----
  {
    const int ETOT = E0 + E1 + E2;
    int nb = (NTOT + 1023) / 1024;
    hipMemsetAsync(cnt, 0, (size_t)2 * NTOT * 4, stream);
    k_count_all<<<(ETOT + 255) / 256, 256, 0, stream>>>(ei[0], ei[1], ei[2], cnt);
    k_blocksum<<<nb, 256, 0, stream>>>(cnt, NTOT, bsums);
    k_scan_bsums<<<1, 256, 0, stream>>>(bsums, nb);
    k_scan_apply<<<nb, 256, 0, stream>>>(cnt, bsums, rowptr, NTOT);
    k_fill_all<<<(ETOT + 255) / 256, 256, 0, stream>>>(ei[0], ei[1], ei[2], rowptr, cur,
                                                       srcs);
  }

  // ---- weight prep (both layers) ----
  {
    dim3 gk(128, 6);
    k_keff<<<gk, 128, 0, stream>>>(qkv_w, qkv_b, W_edge, Keff6, bkeff6);
    dim3 gs(64, 18);
    k_splitw18<<<gs, 256, 0, stream>>>(qkv_w, Keff6, WtHi, WtLo);
  }

  const float scale = 0.08838834764831845f;  // 1/sqrt(128)
  const int GEMM_BLKS = GB0 + GB1 + GB2;
  const int EDGE_BLKS = (NTOT * 16 + 255) / 256;

  for (int l = 0; l < 2; ++l) {
    const f16* Xin = (l == 0) ? XsA : XsB;
    k_gemm3<<<GEMM_BLKS, 256, 0, stream>>>(Xin, WtHi, WtLo, qkv_b, bkeff6, QV, Kb, l);
    if (l == 0)
      k_edge<0><<<EDGE_BLKS, 256, 0, stream>>>(rowptr, srcs, QV, Kb, XsB,
                                               (float*)nullptr, scale);
    else
      k_edge<1><<<EDGE_BLKS, 256, 0, stream>>>(rowptr, srcs, QV, Kb,
                                               (f16*)nullptr, out, scale);
  }
}